// Round 9
// baseline (1041.621 us; speedup 1.0000x reference)
//
#include <hip/hip_runtime.h>
#include <hip/hip_bf16.h>

#define NNODES 200000
#define NEDGES 3200000
#define NBUCK 782            // ceil(NNODES/256)
#define NEB 512              // edge blocks for counting sort
#define EPB (NEDGES / NEB)   // 6250 edges per block
#define EPS 1e-5f
#define AGGB_CHUNK 50000     // nodes per aggb chunk (4 chunks) — diagnostic split
#define AGGF_CHUNK 100000    // nodes per aggf chunk (2 chunks) — diagnostic split

typedef __bf16 bf16x8 __attribute__((ext_vector_type(8)));
typedef float  f32x4  __attribute__((ext_vector_type(4)));
typedef float  f32x2  __attribute__((ext_vector_type(2)));

__device__ __forceinline__ float bflo(unsigned u) { return __uint_as_float(u << 16); }
__device__ __forceinline__ float bfhi(unsigned u) { return __uint_as_float(u & 0xffff0000u); }
__device__ __forceinline__ unsigned short f2b(float f) {
    return __builtin_bit_cast(unsigned short, __float2bfloat16(f));
}
__device__ __forceinline__ unsigned pk2(float a, float b) {
    return (unsigned)f2b(a) | ((unsigned)f2b(b) << 16);
}
// BN+ReLU on a packed bf16 pair, using packed f32 math (v_pk_fma_f32 / v_pk_max_f32)
__device__ __forceinline__ unsigned bnrelu_pk(unsigned u, f32x2 c, f32x2 h) {
    f32x2 v = { __uint_as_float(u << 16), __uint_as_float(u & 0xffff0000u) };
    v = __builtin_elementwise_fma(v, c, h);
    const f32x2 z = {0.f, 0.f};
    v = __builtin_elementwise_max(v, z);
    return pk2(v[0], v[1]);
}

// ---------------- weight swizzle helper ----------------
__device__ __forceinline__ void prepw_one(const float* __restrict__ W,
                                          unsigned short* __restrict__ Wswz,
                                          int K, int NOUT, int t) {
    int KSTEPS = K / 32;
    int lane = t & 63;
    int ks = (t >> 6) % KSTEPS;
    int g  = (t >> 6) / KSTEPS;
    int c = lane & 15, q = lane >> 4;
    int col = g * 16 + c;
    int k0 = ks * 32 + q * 8;
    unsigned short vals[8];
#pragma unroll
    for (int j = 0; j < 8; ++j)
        vals[j] = (col < NOUT) ? f2b(W[(size_t)(k0 + j) * NOUT + col]) : (unsigned short)0;
    *(uint4*)((char*)Wswz + (size_t)t * 16) = __builtin_bit_cast(uint4, vals);
}

// ---------------- CSR build step 1: per-block bucket histogram
// ----------------  + fused weight swizzle + stats zeroing (independent blocks) ----------------
__global__ __launch_bounds__(256) void k_cnt(const int* __restrict__ row, int* __restrict__ cnt,
                                             const float* __restrict__ W1,
                                             const float* __restrict__ W2,
                                             const float* __restrict__ W3,
                                             unsigned short* __restrict__ w1s,
                                             unsigned short* __restrict__ w2s,
                                             unsigned short* __restrict__ w3s,
                                             unsigned* __restrict__ statsz) {
    const int blk = blockIdx.x;
    if (blk == NEB + 54) {                       // zero stats + done counters (1026 dwords)
        for (int i = threadIdx.x; i < 1026; i += 256) statsz[i] = 0u;
        return;
    }
    if (blk >= NEB) {                            // weight swizzle: 54 blocks = 13824 threads
        int t = (blk - NEB) * 256 + threadIdx.x;
        if (t < 4096) prepw_one(W1, w1s, 128, 256, t);
        else if (t < 12288) prepw_one(W2, w2s, 256, 256, t - 4096);
        else if (t < 13824) prepw_one(W3, w3s, 256, 40, t - 12288);
        return;
    }
    __shared__ int h[NBUCK];
    for (int i = threadIdx.x; i < NBUCK; i += 256) h[i] = 0;
    __syncthreads();
    const int e0 = blk * EPB;
    for (int i = e0 + threadIdx.x; i < e0 + EPB; i += 256)
        atomicAdd(&h[row[i] >> 8], 1);
    __syncthreads();
    for (int i = threadIdx.x; i < NBUCK; i += 256)
        cnt[(size_t)blk * NBUCK + i] = h[i];
}

__global__ __launch_bounds__(256) void k_bscan(int* __restrict__ cnt, int* __restrict__ btot) {
    const int wv = (blockIdx.x * 256 + threadIdx.x) >> 6;   // bucket
    const int lane = threadIdx.x & 63;
    if (wv >= NBUCK) return;
    int v[8]; int s = 0;
#pragma unroll
    for (int j = 0; j < 8; ++j) {
        v[j] = cnt[(size_t)(lane * 8 + j) * NBUCK + wv];
        s += v[j];
    }
    int excl = s;
#pragma unroll
    for (int o = 1; o < 64; o <<= 1) {
        int t = __shfl_up(excl, o);
        if (lane >= o) excl += t;
    }
    excl -= s;
    if (lane == 63) btot[wv] = excl + s;
    int base = excl;
#pragma unroll
    for (int j = 0; j < 8; ++j) {
        int t = v[j];
        cnt[(size_t)(lane * 8 + j) * NBUCK + wv] = base;
        base += t;
    }
}

// ---------------- place: in-block scan of btot (replaces k_btscan) + scatter ----------------
__global__ __launch_bounds__(256) void k_place(const int* __restrict__ row, const int* __restrict__ col,
                                               const int* __restrict__ cnt, const int* __restrict__ btot,
                                               int* __restrict__ bbase, unsigned* __restrict__ ebuf) {
    __shared__ int sbb[NBUCK];
    __shared__ int tp[256];
    __shared__ int base[NBUCK];
    const int t = threadIdx.x;
    // chunked exclusive scan of btot[0..NBUCK): thread t owns [t*4, t*4+4)
    int v[4]; int loc = 0;
    const int i0 = t * 4;
#pragma unroll
    for (int j = 0; j < 4; ++j) {
        int idx = i0 + j;
        v[j] = (idx < NBUCK) ? btot[idx] : 0;
        loc += v[j];
    }
    tp[t] = loc;
    __syncthreads();
    for (int off = 1; off < 256; off <<= 1) {
        int u = (t >= off) ? tp[t - off] : 0;
        __syncthreads();
        tp[t] += u;
        __syncthreads();
    }
    int run = tp[t] - loc;   // exclusive prefix of this thread's chunk
#pragma unroll
    for (int j = 0; j < 4; ++j) {
        int idx = i0 + j;
        if (idx < NBUCK) sbb[idx] = run;
        run += v[j];
    }
    __syncthreads();
    if (blockIdx.x == 0) {   // publish for k_sort2
        for (int i = t; i < NBUCK; i += 256) bbase[i] = sbb[i];
        if (t == 0) bbase[NBUCK] = NEDGES;
    }
    for (int i = t; i < NBUCK; i += 256)
        base[i] = sbb[i] + cnt[(size_t)blockIdx.x * NBUCK + i];
    __syncthreads();
    const int e0 = blockIdx.x * EPB;
    for (int i = e0 + t; i < e0 + EPB; i += 256) {
        int r = row[i], c = col[i];
        int p = atomicAdd(&base[r >> 8], 1);
        ebuf[p] = ((unsigned)(r & 255) << 18) | (unsigned)c;   // col < 2^18
    }
}

// fused: per-bucket degree count -> offs/dinv -> rank -> final CSR -> x cast (uses fresh dinv)
__global__ __launch_bounds__(256) void k_sort2(const unsigned* __restrict__ ebuf,
                                               const int* __restrict__ bbase,
                                               int* __restrict__ offs, float* __restrict__ dinv,
                                               int* __restrict__ csr,
                                               const float* __restrict__ x,
                                               uint4* __restrict__ xb) {
    __shared__ int cnt[256];
    __shared__ int sofs[256];
    __shared__ int sc[256];
    __shared__ float sdinv[256];
    const int b = blockIdx.x;
    const int t = threadIdx.x;
    const int n0 = b * 256;
    cnt[t] = 0;
    __syncthreads();
    const int s = bbase[b], e = bbase[b + 1];
    for (int i = s + t; i < e; i += 256)
        atomicAdd(&cnt[ebuf[i] >> 18], 1);
    __syncthreads();
    const int c = cnt[t];
    sc[t] = c;
    __syncthreads();
    for (int off = 1; off < 256; off <<= 1) {
        int v = (t >= off) ? sc[t - off] : 0;
        __syncthreads();
        sc[t] += v;
        __syncthreads();
    }
    const int excl = sc[t] - c;
    sofs[t] = s + excl;
    const int n = n0 + t;
    float dv = rsqrtf((float)(c + 1));
    sdinv[t] = dv;
    if (n < NNODES) {
        offs[n] = s + excl;
        dinv[n] = dv;
    }
    if (b == NBUCK - 1 && t == 0) offs[NNODES] = NEDGES;
    cnt[t] = 0;
    __syncthreads();
    for (int i = s + t; i < e; i += 256) {
        unsigned v = ebuf[i];
        int nl = v >> 18;
        int rank = atomicAdd(&cnt[nl], 1);
        csr[sofs[nl] + rank] = (int)(v & 0x3FFFFu);
    }
    // fused x -> prescaled bf16 cast for this block's nodes (coalesced 128 KB read)
    const int nn = (NNODES - n0 < 256) ? (NNODES - n0) : 256;
    const float4* xp = (const float4*)(x + (size_t)n0 * 128);
    uint4* xo = xb + (size_t)n0 * 16;
    const int lim = nn * 16;
    for (int i = t; i < lim; i += 256) {
        float d = sdinv[i >> 4];
        float4 a = xp[i * 2], bb = xp[i * 2 + 1];
        uint4 o;
        o.x = pk2(a.x * d, a.y * d);  o.y = pk2(a.z * d, a.w * d);
        o.z = pk2(bb.x * d, bb.y * d); o.w = pk2(bb.z * d, bb.w * d);
        xo[i] = o;
    }
}

// ---------------- aggregation: F=128 rows (16 x uint4), up to 16 edges in flight,
// ---------------- node-range chunked (diagnostic split; nodes independent) ----------------
__global__ __launch_bounds__(256) void k_aggf(const uint4* __restrict__ in,
                                              const int* __restrict__ offs,
                                              const int* __restrict__ csr,
                                              const float* __restrict__ dinv,
                                              uint4* __restrict__ out,
                                              int nbase) {
    const int lane = threadIdx.x & 63;
    const int grp = lane >> 4;
    const int fl = lane & 15;
    const int node = nbase + blockIdx.x * 4 + (threadIdx.x >> 6);
    const int p0 = offs[node];
    const int K = offs[node + 1] - p0 + 1;   // +1 virtual self item at k=0
    float a0=0,a1=0,a2=0,a3=0,a4=0,a5=0,a6=0,a7=0;
    auto accum = [&](uint4 u) {
        a0 += bflo(u.x); a1 += bfhi(u.x);
        a2 += bflo(u.y); a3 += bfhi(u.y);
        a4 += bflo(u.z); a5 += bfhi(u.z);
        a6 += bflo(u.w); a7 += bfhi(u.w);
    };
    int k = 0;
    for (; k + 16 <= K; k += 16) {
        int j0 = k + grp;
        int i0 = (j0 == 0) ? node : csr[p0 + j0 - 1];
        int i1 = csr[p0 + k + 3 + grp];
        int i2 = csr[p0 + k + 7 + grp];
        int i3 = csr[p0 + k + 11 + grp];
        uint4 u0 = in[(size_t)i0 * 16 + fl];
        uint4 u1 = in[(size_t)i1 * 16 + fl];
        uint4 u2 = in[(size_t)i2 * 16 + fl];
        uint4 u3 = in[(size_t)i3 * 16 + fl];
        accum(u0); accum(u1); accum(u2); accum(u3);
    }
    for (; k + 8 <= K; k += 8) {
        int j0 = k + grp;
        int i0 = (j0 == 0) ? node : csr[p0 + j0 - 1];
        int i1 = csr[p0 + k + 3 + grp];
        uint4 u0 = in[(size_t)i0 * 16 + fl];
        uint4 u1 = in[(size_t)i1 * 16 + fl];
        accum(u0); accum(u1);
    }
    for (; k + 4 <= K; k += 4) {
        int j0 = k + grp;
        int i0 = (j0 == 0) ? node : csr[p0 + j0 - 1];
        accum(in[(size_t)i0 * 16 + fl]);
    }
    int rem = K - k;
    if (grp < rem) {
        int j0 = k + grp;
        int i0 = (j0 == 0) ? node : csr[p0 + j0 - 1];
        accum(in[(size_t)i0 * 16 + fl]);
    }
#define RED(v) v += __shfl_xor(v, 32); v += __shfl_xor(v, 16);
    RED(a0) RED(a1) RED(a2) RED(a3) RED(a4) RED(a5) RED(a6) RED(a7)
#undef RED
    if (grp == 0) {
        const float d = dinv[node];
        uint4 o;
        o.x = pk2(a0 * d, a1 * d); o.y = pk2(a2 * d, a3 * d);
        o.z = pk2(a4 * d, a5 * d); o.w = pk2(a6 * d, a7 * d);
        out[(size_t)node * 16 + fl] = o;
    }
}

// ---------------- aggregation: F=256 rows (32 x uint4), 2 edges per load, unroll 4,
// ---------------- node-range chunked (diagnostic split; nodes independent) ----------------
__global__ __launch_bounds__(256) void k_aggb(const uint4* __restrict__ in,
                                              const int* __restrict__ offs,
                                              const int* __restrict__ csr,
                                              const float* __restrict__ dinv,
                                              uint4* __restrict__ out,
                                              int nbase) {
    const int lane = threadIdx.x & 63;
    const int half = lane >> 5;
    const int fl = lane & 31;
    const int node = nbase + blockIdx.x * 4 + (threadIdx.x >> 6);
    const int p0 = offs[node];
    const int K = offs[node + 1] - p0 + 1;
    float a0=0,a1=0,a2=0,a3=0,a4=0,a5=0,a6=0,a7=0;
    auto accum = [&](uint4 u) {
        a0 += bflo(u.x); a1 += bfhi(u.x);
        a2 += bflo(u.y); a3 += bfhi(u.y);
        a4 += bflo(u.z); a5 += bfhi(u.z);
        a6 += bflo(u.w); a7 += bfhi(u.w);
    };
    auto idxAt = [&](int j) -> int { return (j == 0) ? node : csr[p0 + j - 1]; };
    int k = 0;
    for (; k + 8 <= K; k += 8) {
        int i0 = idxAt(k + half);
        int i1 = csr[p0 + k + 1 + half];
        int i2 = csr[p0 + k + 3 + half];
        int i3 = csr[p0 + k + 5 + half];
        uint4 u0 = in[(size_t)i0 * 32 + fl];
        uint4 u1 = in[(size_t)i1 * 32 + fl];
        uint4 u2 = in[(size_t)i2 * 32 + fl];
        uint4 u3 = in[(size_t)i3 * 32 + fl];
        accum(u0); accum(u1); accum(u2); accum(u3);
    }
    for (; k + 2 <= K; k += 2) {
        accum(in[(size_t)idxAt(k + half) * 32 + fl]);
    }
    if (k < K && half == 0) {
        accum(in[(size_t)idxAt(k) * 32 + fl]);
    }
#define RED(v) v += __shfl_xor(v, 32);
    RED(a0) RED(a1) RED(a2) RED(a3) RED(a4) RED(a5) RED(a6) RED(a7)
#undef RED
    if (half == 0) {
        const float d = dinv[node];
        uint4 o;
        o.x = pk2(a0 * d, a1 * d); o.y = pk2(a2 * d, a3 * d);
        o.z = pk2(a4 * d, a5 * d); o.w = pk2(a6 * d, a7 * d);
        out[(size_t)node * 32 + fl] = o;
    }
}

// ---------------- final layer: 40-feat rows padded to 128 B (stride 64 bf16) + log_softmax ----------------
__global__ __launch_bounds__(256) void k_agg3(const uint4* __restrict__ T3b,
                                              const int* __restrict__ offs,
                                              const int* __restrict__ csr,
                                              const float* __restrict__ dinv,
                                              const float* __restrict__ b3,
                                              float* __restrict__ out) {
    const int lane = threadIdx.x & 63;
    const int grp = lane / 5;
    const int fl = lane - grp * 5;
    const bool act = grp < 12;
    const int node = blockIdx.x * 4 + (threadIdx.x >> 6);
    const int p0 = offs[node];
    const int K = offs[node + 1] - p0 + 1;
    float a0=0,a1=0,a2=0,a3=0,a4=0,a5=0,a6=0,a7=0;
    auto accum = [&](uint4 u) {
        a0 += bflo(u.x); a1 += bfhi(u.x);
        a2 += bflo(u.y); a3 += bfhi(u.y);
        a4 += bflo(u.z); a5 += bfhi(u.z);
        a6 += bflo(u.w); a7 += bfhi(u.w);
    };
    const char* Tb = (const char*)T3b;
    int k = 0;
    if (act) {
        for (; k + 12 <= K; k += 12) {
            int j = k + grp;
            int i0 = (j == 0) ? node : csr[p0 + j - 1];
            accum(*(const uint4*)(Tb + (size_t)i0 * 128 + fl * 16));
        }
        int rem = K - k;
        if (grp < rem) {
            int j = k + grp;
            int i0 = (j == 0) ? node : csr[p0 + j - 1];
            accum(*(const uint4*)(Tb + (size_t)i0 * 128 + fl * 16));
        }
    }
#define RED3(v) { float t = __shfl(v, lane + 30); v += t; t = __shfl(v, lane + 15); v += t; \
                  float u1 = __shfl(v, lane + 5); float u2 = __shfl(v, lane + 10); v += u1 + u2; }
    RED3(a0) RED3(a1) RED3(a2) RED3(a3) RED3(a4) RED3(a5) RED3(a6) RED3(a7)
#undef RED3
    const float d = dinv[node];
    float v[8];
    if (grp == 0) {
        const float4* bp = (const float4*)(b3 + fl * 8);
        float4 b01 = bp[0], b23 = bp[1];
        v[0] = a0 * d + b01.x; v[1] = a1 * d + b01.y;
        v[2] = a2 * d + b01.z; v[3] = a3 * d + b01.w;
        v[4] = a4 * d + b23.x; v[5] = a5 * d + b23.y;
        v[6] = a6 * d + b23.z; v[7] = a7 * d + b23.w;
    } else {
#pragma unroll
        for (int j = 0; j < 8; ++j) v[j] = -INFINITY;
    }
    float m = v[0];
#pragma unroll
    for (int j = 1; j < 8; ++j) m = fmaxf(m, v[j]);
    float mm = __shfl(m, 0);
#pragma unroll
    for (int l = 1; l < 5; ++l) mm = fmaxf(mm, __shfl(m, l));
    float e = 0.f;
    if (grp == 0) {
#pragma unroll
        for (int j = 0; j < 8; ++j) e += __expf(v[j] - mm);
    }
    float s = __shfl(e, 0);
#pragma unroll
    for (int l = 1; l < 5; ++l) s += __shfl(e, l);
    float ls = __logf(s);
    if (grp == 0) {
        float* op = out + (size_t)node * 40 + fl * 8;
        float4 o0 = {v[0] - mm - ls, v[1] - mm - ls, v[2] - mm - ls, v[3] - mm - ls};
        float4 o1 = {v[4] - mm - ls, v[5] - mm - ls, v[6] - mm - ls, v[7] - mm - ls};
        *(float4*)op = o0;
        *(float4*)(op + 4) = o1;
    }
}

// ---------------- MFMA GEMM, LDS-staged A (double-buffered), BN+ReLU applied ONCE at staging,
// ---------------- dinv prescale on C, optional fused column stats + BN finalize ----------------
template <int K, int MW, int NW, int WNB, bool PRESCALE, bool BNA, bool STATS>
__global__ __launch_bounds__(MW * NW * 64) void k_gemm(const __hip_bfloat16* __restrict__ A,
                                                       const __hip_bfloat16* __restrict__ Wswz,
                                                       const float* __restrict__ dinvp,
                                                       const float* __restrict__ bnsc,
                                                       const float* __restrict__ bnsh,
                                                       unsigned short* __restrict__ Cout,
                                                       int M, int NOUT, int CS,
                                                       float* __restrict__ sums,
                                                       float* __restrict__ sq,
                                                       const float* __restrict__ gamma,
                                                       const float* __restrict__ beta,
                                                       float* __restrict__ scale,
                                                       float* __restrict__ shift,
                                                       int* __restrict__ done) {
    constexpr int KSTEPS = K / 32;
    constexpr int NTHR   = MW * NW * 64;
    constexpr int ROWS   = MW * 64;                       // A-tile rows per block
    constexpr int STAGE_U4 = (ROWS * 64) / (NTHR * 16);   // uint4 staged per thread per k-slice
    __shared__ __align__(16) unsigned short As[2][ROWS * 32];   // [buf][row*32 + col]

    const int t = threadIdx.x;
    const int lane = t & 63;
    const int wid  = t >> 6;
    const int wm = (wid % MW) * 64;
    const int wn = (wid / MW) * (WNB * 16);
    const long rowBase = (long)blockIdx.x * ROWS;
    const int cl = lane & 15, q = lane >> 4;
    const int colq = t & 3;                               // staging col-quarter (16B)

    const __hip_bfloat16* bptr[WNB];
#pragma unroll
    for (int nf = 0; nf < WNB; ++nf) {
        int g = wn / 16 + nf;
        bptr[nf] = Wswz + (size_t)g * KSTEPS * 512 + (size_t)lane * 8;
    }

    uint4 stg[STAGE_U4];
    auto stage_ld = [&](int ks) {
#pragma unroll
        for (int u = 0; u < STAGE_U4; ++u) {
            int rg = (t >> 2) + u * (NTHR >> 2);
            long r = rowBase + rg; if (r > M - 1) r = M - 1;
            stg[u] = *(const uint4*)((const char*)A + (size_t)r * (K * 2) + ks * 64 + colq * 16);
        }
    };
    auto stage_st = [&](int ks, int bsel) {
        f32x2 cp[4], hp[4];
        if constexpr (BNA) {
            const f32x2* cpp = (const f32x2*)(bnsc + ks * 32 + colq * 8);
            const f32x2* hpp = (const f32x2*)(bnsh + ks * 32 + colq * 8);
#pragma unroll
            for (int j = 0; j < 4; ++j) { cp[j] = cpp[j]; hp[j] = hpp[j]; }
        }
#pragma unroll
        for (int u = 0; u < STAGE_U4; ++u) {
            uint4 v = stg[u];
            if constexpr (BNA) {
                v.x = bnrelu_pk(v.x, cp[0], hp[0]);
                v.y = bnrelu_pk(v.y, cp[1], hp[1]);
                v.z = bnrelu_pk(v.z, cp[2], hp[2]);
                v.w = bnrelu_pk(v.w, cp[3], hp[3]);
            }
            int rg = (t >> 2) + u * (NTHR >> 2);
            *(uint4*)&As[bsel][rg * 32 + colq * 8] = v;
        }
    };

    f32x4 acc[4][WNB];
    const f32x4 z = {0.f, 0.f, 0.f, 0.f};
#pragma unroll
    for (int mf = 0; mf < 4; ++mf)
#pragma unroll
        for (int nf = 0; nf < WNB; ++nf) acc[mf][nf] = z;

    stage_ld(0);
    stage_st(0, 0);
    __syncthreads();

#pragma unroll
    for (int ks = 0; ks < KSTEPS; ++ks) {
        const int cur = ks & 1;
        if (ks + 1 < KSTEPS) stage_ld(ks + 1);    // issue next slice's global loads early
        bf16x8 a[4], b[WNB];
#pragma unroll
        for (int nf = 0; nf < WNB; ++nf)
            b[nf] = __builtin_bit_cast(bf16x8, *(const uint4*)(bptr[nf] + ks * 512));
#pragma unroll
        for (int mf = 0; mf < 4; ++mf)
            a[mf] = __builtin_bit_cast(bf16x8, *(const uint4*)&As[cur][(wm + mf * 16 + cl) * 32 + q * 8]);
#pragma unroll
        for (int mf = 0; mf < 4; ++mf)
#pragma unroll
            for (int nf = 0; nf < WNB; ++nf)
                acc[mf][nf] = __builtin_amdgcn_mfma_f32_16x16x32_bf16(a[mf], b[nf], acc[mf][nf], 0, 0, 0);
        if (ks + 1 < KSTEPS) {
            stage_st(ks + 1, cur ^ 1);
            __syncthreads();
        }
    }

#pragma unroll
    for (int mf = 0; mf < 4; ++mf)
#pragma unroll
        for (int i = 0; i < 4; ++i) {
            long row = rowBase + wm + mf * 16 + q * 4 + i;
            if (row >= M) continue;
            float dv = PRESCALE ? dinvp[row] : 1.0f;
#pragma unroll
            for (int nf = 0; nf < WNB; ++nf) {
                int col = wn + nf * 16 + cl;
                if (col < NOUT)
                    Cout[row * CS + col] = f2b(PRESCALE ? acc[mf][nf][i] * dv : acc[mf][nf][i]);
            }
        }

    if constexpr (STATS) {
        // per-column partial sums over this block's rows (M % 64 == 0, no padding rows)
#pragma unroll
        for (int nf = 0; nf < WNB; ++nf) {
            float s = 0.f, s2 = 0.f;
#pragma unroll
            for (int mf = 0; mf < 4; ++mf)
#pragma unroll
                for (int i = 0; i < 4; ++i) {
                    long row = rowBase + wm + mf * 16 + q * 4 + i;
                    float v = (row < M) ? acc[mf][nf][i] : 0.f;
                    s += v; s2 += v * v;
                }
            s  += __shfl_xor(s, 16);  s  += __shfl_xor(s, 32);
            s2 += __shfl_xor(s2, 16); s2 += __shfl_xor(s2, 32);
            if (q == 0) {
                int col = wn + nf * 16 + cl;
                if (col < NOUT) {
                    atomicAdd(&sums[col], s);
                    atomicAdd(&sq[col], s2);
                }
            }
        }
        __syncthreads();                       // drains this block's atomics before done
        __shared__ int lastf;
        if (threadIdx.x == 0) lastf = (atomicAdd(done, 1) == (int)gridDim.x - 1) ? 1 : 0;
        __syncthreads();
        if (lastf) {
            const int tt = threadIdx.x;        // 256 threads
            float su = atomicAdd(&sums[tt], 0.0f);   // L2-coherent read
            float qu = atomicAdd(&sq[tt], 0.0f);
            float mu = su * (1.0f / NNODES);
            float var = qu * (1.0f / NNODES) - mu * mu;
            if (var < 0.f) var = 0.f;
            float sc = gamma[tt] * rsqrtf(var + EPS);
            scale[tt] = sc;
            shift[tt] = beta[tt] - mu * sc;
        }
    }
}

// ---------------- BN stats over bf16 matrix, vectorized + done-counter finalize ----------------
__global__ __launch_bounds__(256) void k_stats(const uint4* __restrict__ Zu,
                                               float* __restrict__ sums, float* __restrict__ sq,
                                               const float* __restrict__ gamma,
                                               const float* __restrict__ beta,
                                               float* __restrict__ scale, float* __restrict__ shift,
                                               int* __restrict__ done) {
    __shared__ float reds[8][256];
    __shared__ float redq[8][256];
    const int t = threadIdx.x;
    const int cg = t & 31;        // col group: cols cg*8 .. cg*8+7
    const int rs = t >> 5;        // row slice: rows rs*32 .. rs*32+31 of this block's 256
    const long r0 = (long)blockIdx.x * 256 + (long)rs * 32;
    float s[8], q[8];
#pragma unroll
    for (int j = 0; j < 8; ++j) { s[j] = 0.f; q[j] = 0.f; }
    for (int i = 0; i < 32; ++i) {
        long r = r0 + i;
        if (r >= NNODES) break;
        uint4 u = Zu[r * 32 + cg];
        float v0 = bflo(u.x), v1 = bfhi(u.x), v2 = bflo(u.y), v3 = bfhi(u.y);
        float v4 = bflo(u.z), v5 = bfhi(u.z), v6 = bflo(u.w), v7 = bfhi(u.w);
        s[0] += v0; q[0] += v0 * v0;  s[1] += v1; q[1] += v1 * v1;
        s[2] += v2; q[2] += v2 * v2;  s[3] += v3; q[3] += v3 * v3;
        s[4] += v4; q[4] += v4 * v4;  s[5] += v5; q[5] += v5 * v5;
        s[6] += v6; q[6] += v6 * v6;  s[7] += v7; q[7] += v7 * v7;
    }
#pragma unroll
    for (int j = 0; j < 8; ++j) {
        reds[rs][cg * 8 + j] = s[j];
        redq[rs][cg * 8 + j] = q[j];
    }
    __syncthreads();
    float S = 0.f, Q = 0.f;
#pragma unroll
    for (int j = 0; j < 8; ++j) { S += reds[j][t]; Q += redq[j][t]; }
    atomicAdd(&sums[t], S);
    atomicAdd(&sq[t], Q);
    __syncthreads();                       // drains this block's atomics before done
    __shared__ int lastf;
    if (t == 0) lastf = (atomicAdd(done, 1) == (int)gridDim.x - 1) ? 1 : 0;
    __syncthreads();
    if (lastf) {
        float su = atomicAdd(&sums[t], 0.0f);
        float qu = atomicAdd(&sq[t], 0.0f);
        float mu = su * (1.0f / NNODES);
        float var = qu * (1.0f / NNODES) - mu * mu;
        if (var < 0.f) var = 0.f;
        float sc = gamma[t] * rsqrtf(var + EPS);
        scale[t] = sc;
        shift[t] = beta[t] - mu * sc;
    }
}

// ---------------- driver ----------------
extern "C" void kernel_launch(void* const* d_in, const int* in_sizes, int n_in,
                              void* d_out, int out_size, void* d_ws, size_t ws_size,
                              hipStream_t stream) {
    const float* x   = (const float*)d_in[0];
    const int*   ei  = (const int*)d_in[1];
    const float* W1  = (const float*)d_in[2];
    const float* g1  = (const float*)d_in[4];
    const float* be1 = (const float*)d_in[5];
    const float* W2  = (const float*)d_in[6];
    const float* g2  = (const float*)d_in[8];
    const float* be2 = (const float*)d_in[9];
    const float* W3  = (const float*)d_in[10];
    const float* b3  = (const float*)d_in[11];
    // b1 (d_in[3]) and b2 (d_in[7]) cancel exactly under BatchNorm — skipped.

    char* w = (char*)d_ws;
    size_t o = 0;
    auto alloc = [&](size_t b) { size_t r = o; o += (b + 255) & ~(size_t)255; return r; };
    int*   offs = (int*)(w + alloc((size_t)(NNODES + 1) * 4));
    float* dinv = (float*)(w + alloc((size_t)NNODES * 4));
    int*   cnt  = (int*)(w + alloc((size_t)NEB * NBUCK * 4));   // 1.6 MB
    int*   btot = (int*)(w + alloc(NBUCK * 4));
    int*   bbase= (int*)(w + alloc((NBUCK + 1) * 4));
    unsigned* ebuf = (unsigned*)(w + alloc((size_t)NEDGES * 4));
    int*   csr  = (int*)(w + alloc((size_t)NEDGES * 4));
    float* stats = (float*)(w + alloc(4 * 256 * 4 + 32));       // sums1,sq1,sums2,sq2,done1,done2
    float* bnp   = (float*)(w + alloc(4 * 256 * 4));            // scale1,shift1,scale2,shift2
    unsigned short* w1s = (unsigned short*)(w + alloc(65536));
    unsigned short* w2s = (unsigned short*)(w + alloc(131072));
    unsigned short* w3s = (unsigned short*)(w + alloc(24576));
    __hip_bfloat16* xb   = (__hip_bfloat16*)(w + alloc((size_t)NNODES * 128 * 2));
    __hip_bfloat16* buf0 = (__hip_bfloat16*)(w + alloc((size_t)NNODES * 128 * 2)); // y0 -> T3' (stride 64)
    __hip_bfloat16* buf1 = (__hip_bfloat16*)(w + alloc((size_t)NNODES * 256 * 2)); // Z1 -> Z2
    __hip_bfloat16* buf2 = (__hip_bfloat16*)(w + alloc((size_t)NNODES * 256 * 2)); // y2'

    float* sums1 = stats;       float* sq1 = stats + 256;
    float* sums2 = stats + 512; float* sq2 = stats + 768;
    int*   done1 = (int*)(stats + 1024);
    int*   done2 = done1 + 1;
    float* scale1 = bnp;        float* shift1 = bnp + 256;
    float* scale2 = bnp + 512;  float* shift2 = bnp + 768;

    const int SB = (NNODES + 255) / 256;  // 782

    // CSR build + fused weight swizzle + stats zeroing (no memset dispatch)
    k_cnt<<<NEB + 55, 256, 0, stream>>>(ei, cnt, W1, W2, W3, w1s, w2s, w3s, (unsigned*)stats);
    k_bscan<<<(NBUCK * 64 + 255) / 256, 256, 0, stream>>>(cnt, btot);
    k_place<<<NEB, 256, 0, stream>>>(ei, ei + NEDGES, cnt, btot, bbase, ebuf);
    k_sort2<<<NBUCK, 256, 0, stream>>>(ebuf, bbase, offs, dinv, csr, x, (uint4*)xb);

    const dim3 g64((NNODES + 63) / 64, 1);

    // layer 1: BN1 stats fused into GEMM epilogue, finalized by last block (done-counter);
    // aggf split into 2 node-range chunks (diagnostic: keeps top-5 informative)
    for (int c = 0; c < 2; ++c)
        k_aggf<<<AGGF_CHUNK / 4, 256, 0, stream>>>((const uint4*)xb, offs, csr, dinv, (uint4*)buf0, c * AGGF_CHUNK);
    k_gemm<128, 1, 4, 4, false, false, true><<<g64, 256, 0, stream>>>(buf0, (const __hip_bfloat16*)w1s, nullptr, nullptr, nullptr, (unsigned short*)buf1, NNODES, 256, 256, sums1, sq1, g1, be1, scale1, shift1, done1);

    // layer 2: gemm2 applies BN1+ReLU once at LDS staging, prescales C by dinv;
    // aggb split into 4 node-range chunks (diagnostic)
    k_gemm<256, 1, 4, 4, true, true, false><<<g64, 256, 0, stream>>>(buf1, (const __hip_bfloat16*)w2s, dinv, scale1, shift1, (unsigned short*)buf2, NNODES, 256, 256, nullptr, nullptr, nullptr, nullptr, nullptr, nullptr, nullptr);
    for (int c = 0; c < 4; ++c)
        k_aggb<<<AGGB_CHUNK / 4, 256, 0, stream>>>((const uint4*)buf2, offs, csr, dinv, (uint4*)buf1, c * AGGB_CHUNK);
    k_stats<<<SB, 256, 0, stream>>>((const uint4*)buf1, sums2, sq2, g2, be2, scale2, shift2, done2);

    // layer 3: gemm3 applies BN2+ReLU once at LDS staging, prescales C by dinv, writes 128B-padded rows;
    // then fused agg+softmax reads exactly one cache line per gathered row
    k_gemm<256, 4, 1, 3, true, true, false><<<dim3((NNODES + 255) / 256, 1), 256, 0, stream>>>(buf1, (const __hip_bfloat16*)w3s, dinv, scale2, shift2, (unsigned short*)buf0, NNODES, 40, 64, nullptr, nullptr, nullptr, nullptr, nullptr, nullptr, nullptr);
    k_agg3<<<NNODES / 4, 256, 0, stream>>>((const uint4*)buf0, offs, csr, dinv, b3, (float*)d_out);
}

// Round 10
// 1009.989 us; speedup vs baseline: 1.0313x; 1.0313x over previous
//
#include <hip/hip_runtime.h>
#include <hip/hip_bf16.h>

#define NNODES 200000
#define NEDGES 3200000
#define NBUCK 782            // ceil(NNODES/256)
#define NEB 512              // edge blocks for counting sort
#define EPB (NEDGES / NEB)   // 6250 edges per block
#define EPS 1e-5f
#define AGGB_CHUNK 50000     // nodes per aggb chunk (4 chunks) — diagnostic split
#define AGGF_CHUNK 100000    // nodes per aggf chunk (2 chunks) — diagnostic split

typedef __bf16 bf16x8 __attribute__((ext_vector_type(8)));
typedef float  f32x4  __attribute__((ext_vector_type(4)));
typedef float  f32x2  __attribute__((ext_vector_type(2)));

__device__ __forceinline__ float bflo(unsigned u) { return __uint_as_float(u << 16); }
__device__ __forceinline__ float bfhi(unsigned u) { return __uint_as_float(u & 0xffff0000u); }
__device__ __forceinline__ unsigned short f2b(float f) {
    return __builtin_bit_cast(unsigned short, __float2bfloat16(f));
}
__device__ __forceinline__ unsigned pk2(float a, float b) {
    return (unsigned)f2b(a) | ((unsigned)f2b(b) << 16);
}
// BN+ReLU on a packed bf16 pair, using packed f32 math (v_pk_fma_f32 / v_pk_max_f32)
__device__ __forceinline__ unsigned bnrelu_pk(unsigned u, f32x2 c, f32x2 h) {
    f32x2 v = { __uint_as_float(u << 16), __uint_as_float(u & 0xffff0000u) };
    v = __builtin_elementwise_fma(v, c, h);
    const f32x2 z = {0.f, 0.f};
    v = __builtin_elementwise_max(v, z);
    return pk2(v[0], v[1]);
}

// ---------------- weight swizzle helper ----------------
__device__ __forceinline__ void prepw_one(const float* __restrict__ W,
                                          unsigned short* __restrict__ Wswz,
                                          int K, int NOUT, int t) {
    int KSTEPS = K / 32;
    int lane = t & 63;
    int ks = (t >> 6) % KSTEPS;
    int g  = (t >> 6) / KSTEPS;
    int c = lane & 15, q = lane >> 4;
    int col = g * 16 + c;
    int k0 = ks * 32 + q * 8;
    unsigned short vals[8];
#pragma unroll
    for (int j = 0; j < 8; ++j)
        vals[j] = (col < NOUT) ? f2b(W[(size_t)(k0 + j) * NOUT + col]) : (unsigned short)0;
    *(uint4*)((char*)Wswz + (size_t)t * 16) = __builtin_bit_cast(uint4, vals);
}

// ---------------- CSR build step 1: per-block bucket histogram
// ----------------  + fused weight swizzle + stats zeroing (independent blocks) ----------------
__global__ __launch_bounds__(256) void k_cnt(const int* __restrict__ row, int* __restrict__ cnt,
                                             const float* __restrict__ W1,
                                             const float* __restrict__ W2,
                                             const float* __restrict__ W3,
                                             unsigned short* __restrict__ w1s,
                                             unsigned short* __restrict__ w2s,
                                             unsigned short* __restrict__ w3s,
                                             unsigned* __restrict__ statsz) {
    const int blk = blockIdx.x;
    if (blk == NEB + 56) {                       // zero stats + done counters (1026 dwords)
        for (int i = threadIdx.x; i < 1026; i += 256) statsz[i] = 0u;
        return;
    }
    if (blk >= NEB) {                            // weight swizzle: 56 blocks = 14336 threads
        int t = (blk - NEB) * 256 + threadIdx.x;
        if (t < 4096) prepw_one(W1, w1s, 128, 256, t);
        else if (t < 12288) prepw_one(W2, w2s, 256, 256, t - 4096);
        else if (t < 14336) prepw_one(W3, w3s, 256, 40, t - 12288);   // 4 col-groups, zero-padded
        return;
    }
    __shared__ int h[NBUCK];
    for (int i = threadIdx.x; i < NBUCK; i += 256) h[i] = 0;
    __syncthreads();
    const int e0 = blk * EPB;
    for (int i = e0 + threadIdx.x; i < e0 + EPB; i += 256)
        atomicAdd(&h[row[i] >> 8], 1);
    __syncthreads();
    for (int i = threadIdx.x; i < NBUCK; i += 256)
        cnt[(size_t)blk * NBUCK + i] = h[i];
}

__global__ __launch_bounds__(256) void k_bscan(int* __restrict__ cnt, int* __restrict__ btot) {
    const int wv = (blockIdx.x * 256 + threadIdx.x) >> 6;   // bucket
    const int lane = threadIdx.x & 63;
    if (wv >= NBUCK) return;
    int v[8]; int s = 0;
#pragma unroll
    for (int j = 0; j < 8; ++j) {
        v[j] = cnt[(size_t)(lane * 8 + j) * NBUCK + wv];
        s += v[j];
    }
    int excl = s;
#pragma unroll
    for (int o = 1; o < 64; o <<= 1) {
        int t = __shfl_up(excl, o);
        if (lane >= o) excl += t;
    }
    excl -= s;
    if (lane == 63) btot[wv] = excl + s;
    int base = excl;
#pragma unroll
    for (int j = 0; j < 8; ++j) {
        int t = v[j];
        cnt[(size_t)(lane * 8 + j) * NBUCK + wv] = base;
        base += t;
    }
}

// ---------------- place: in-block scan of btot (replaces k_btscan) + scatter ----------------
__global__ __launch_bounds__(256) void k_place(const int* __restrict__ row, const int* __restrict__ col,
                                               const int* __restrict__ cnt, const int* __restrict__ btot,
                                               int* __restrict__ bbase, unsigned* __restrict__ ebuf) {
    __shared__ int sbb[NBUCK];
    __shared__ int tp[256];
    __shared__ int base[NBUCK];
    const int t = threadIdx.x;
    // chunked exclusive scan of btot[0..NBUCK): thread t owns [t*4, t*4+4)
    int v[4]; int loc = 0;
    const int i0 = t * 4;
#pragma unroll
    for (int j = 0; j < 4; ++j) {
        int idx = i0 + j;
        v[j] = (idx < NBUCK) ? btot[idx] : 0;
        loc += v[j];
    }
    tp[t] = loc;
    __syncthreads();
    for (int off = 1; off < 256; off <<= 1) {
        int u = (t >= off) ? tp[t - off] : 0;
        __syncthreads();
        tp[t] += u;
        __syncthreads();
    }
    int run = tp[t] - loc;   // exclusive prefix of this thread's chunk
#pragma unroll
    for (int j = 0; j < 4; ++j) {
        int idx = i0 + j;
        if (idx < NBUCK) sbb[idx] = run;
        run += v[j];
    }
    __syncthreads();
    if (blockIdx.x == 0) {   // publish for k_sort2
        for (int i = t; i < NBUCK; i += 256) bbase[i] = sbb[i];
        if (t == 0) bbase[NBUCK] = NEDGES;
    }
    for (int i = t; i < NBUCK; i += 256)
        base[i] = sbb[i] + cnt[(size_t)blockIdx.x * NBUCK + i];
    __syncthreads();
    const int e0 = blockIdx.x * EPB;
    for (int i = e0 + t; i < e0 + EPB; i += 256) {
        int r = row[i], c = col[i];
        int p = atomicAdd(&base[r >> 8], 1);
        ebuf[p] = ((unsigned)(r & 255) << 18) | (unsigned)c;   // col < 2^18
    }
}

// fused: per-bucket degree count -> offs/dinv -> rank -> final CSR -> x cast (uses fresh dinv)
__global__ __launch_bounds__(256) void k_sort2(const unsigned* __restrict__ ebuf,
                                               const int* __restrict__ bbase,
                                               int* __restrict__ offs, float* __restrict__ dinv,
                                               int* __restrict__ csr,
                                               const float* __restrict__ x,
                                               uint4* __restrict__ xb) {
    __shared__ int cnt[256];
    __shared__ int sofs[256];
    __shared__ int sc[256];
    __shared__ float sdinv[256];
    const int b = blockIdx.x;
    const int t = threadIdx.x;
    const int n0 = b * 256;
    cnt[t] = 0;
    __syncthreads();
    const int s = bbase[b], e = bbase[b + 1];
    for (int i = s + t; i < e; i += 256)
        atomicAdd(&cnt[ebuf[i] >> 18], 1);
    __syncthreads();
    const int c = cnt[t];
    sc[t] = c;
    __syncthreads();
    for (int off = 1; off < 256; off <<= 1) {
        int v = (t >= off) ? sc[t - off] : 0;
        __syncthreads();
        sc[t] += v;
        __syncthreads();
    }
    const int excl = sc[t] - c;
    sofs[t] = s + excl;
    const int n = n0 + t;
    float dv = rsqrtf((float)(c + 1));
    sdinv[t] = dv;
    if (n < NNODES) {
        offs[n] = s + excl;
        dinv[n] = dv;
    }
    if (b == NBUCK - 1 && t == 0) offs[NNODES] = NEDGES;
    cnt[t] = 0;
    __syncthreads();
    for (int i = s + t; i < e; i += 256) {
        unsigned v = ebuf[i];
        int nl = v >> 18;
        int rank = atomicAdd(&cnt[nl], 1);
        csr[sofs[nl] + rank] = (int)(v & 0x3FFFFu);
    }
    // fused x -> prescaled bf16 cast for this block's nodes (coalesced 128 KB read)
    const int nn = (NNODES - n0 < 256) ? (NNODES - n0) : 256;
    const float4* xp = (const float4*)(x + (size_t)n0 * 128);
    uint4* xo = xb + (size_t)n0 * 16;
    const int lim = nn * 16;
    for (int i = t; i < lim; i += 256) {
        float d = sdinv[i >> 4];
        float4 a = xp[i * 2], bb = xp[i * 2 + 1];
        uint4 o;
        o.x = pk2(a.x * d, a.y * d);  o.y = pk2(a.z * d, a.w * d);
        o.z = pk2(bb.x * d, bb.y * d); o.w = pk2(bb.z * d, bb.w * d);
        xo[i] = o;
    }
}

// ---------------- aggregation: F=128 rows (16 x uint4), up to 16 edges in flight,
// ---------------- node-range chunked (diagnostic split; nodes independent) ----------------
__global__ __launch_bounds__(256) void k_aggf(const uint4* __restrict__ in,
                                              const int* __restrict__ offs,
                                              const int* __restrict__ csr,
                                              const float* __restrict__ dinv,
                                              uint4* __restrict__ out,
                                              int nbase) {
    const int lane = threadIdx.x & 63;
    const int grp = lane >> 4;
    const int fl = lane & 15;
    const int node = nbase + blockIdx.x * 4 + (threadIdx.x >> 6);
    const int p0 = offs[node];
    const int K = offs[node + 1] - p0 + 1;   // +1 virtual self item at k=0
    float a0=0,a1=0,a2=0,a3=0,a4=0,a5=0,a6=0,a7=0;
    auto accum = [&](uint4 u) {
        a0 += bflo(u.x); a1 += bfhi(u.x);
        a2 += bflo(u.y); a3 += bfhi(u.y);
        a4 += bflo(u.z); a5 += bfhi(u.z);
        a6 += bflo(u.w); a7 += bfhi(u.w);
    };
    int k = 0;
    for (; k + 16 <= K; k += 16) {
        int j0 = k + grp;
        int i0 = (j0 == 0) ? node : csr[p0 + j0 - 1];
        int i1 = csr[p0 + k + 3 + grp];
        int i2 = csr[p0 + k + 7 + grp];
        int i3 = csr[p0 + k + 11 + grp];
        uint4 u0 = in[(size_t)i0 * 16 + fl];
        uint4 u1 = in[(size_t)i1 * 16 + fl];
        uint4 u2 = in[(size_t)i2 * 16 + fl];
        uint4 u3 = in[(size_t)i3 * 16 + fl];
        accum(u0); accum(u1); accum(u2); accum(u3);
    }
    for (; k + 8 <= K; k += 8) {
        int j0 = k + grp;
        int i0 = (j0 == 0) ? node : csr[p0 + j0 - 1];
        int i1 = csr[p0 + k + 3 + grp];
        uint4 u0 = in[(size_t)i0 * 16 + fl];
        uint4 u1 = in[(size_t)i1 * 16 + fl];
        accum(u0); accum(u1);
    }
    for (; k + 4 <= K; k += 4) {
        int j0 = k + grp;
        int i0 = (j0 == 0) ? node : csr[p0 + j0 - 1];
        accum(in[(size_t)i0 * 16 + fl]);
    }
    int rem = K - k;
    if (grp < rem) {
        int j0 = k + grp;
        int i0 = (j0 == 0) ? node : csr[p0 + j0 - 1];
        accum(in[(size_t)i0 * 16 + fl]);
    }
#define RED(v) v += __shfl_xor(v, 32); v += __shfl_xor(v, 16);
    RED(a0) RED(a1) RED(a2) RED(a3) RED(a4) RED(a5) RED(a6) RED(a7)
#undef RED
    if (grp == 0) {
        const float d = dinv[node];
        uint4 o;
        o.x = pk2(a0 * d, a1 * d); o.y = pk2(a2 * d, a3 * d);
        o.z = pk2(a4 * d, a5 * d); o.w = pk2(a6 * d, a7 * d);
        out[(size_t)node * 16 + fl] = o;
    }
}

// ---------------- aggregation: F=256 rows (32 x uint4), 2 edges per load, unroll 4,
// ---------------- node-range chunked (diagnostic split; nodes independent) ----------------
__global__ __launch_bounds__(256) void k_aggb(const uint4* __restrict__ in,
                                              const int* __restrict__ offs,
                                              const int* __restrict__ csr,
                                              const float* __restrict__ dinv,
                                              uint4* __restrict__ out,
                                              int nbase) {
    const int lane = threadIdx.x & 63;
    const int half = lane >> 5;
    const int fl = lane & 31;
    const int node = nbase + blockIdx.x * 4 + (threadIdx.x >> 6);
    const int p0 = offs[node];
    const int K = offs[node + 1] - p0 + 1;
    float a0=0,a1=0,a2=0,a3=0,a4=0,a5=0,a6=0,a7=0;
    auto accum = [&](uint4 u) {
        a0 += bflo(u.x); a1 += bfhi(u.x);
        a2 += bflo(u.y); a3 += bfhi(u.y);
        a4 += bflo(u.z); a5 += bfhi(u.z);
        a6 += bflo(u.w); a7 += bfhi(u.w);
    };
    auto idxAt = [&](int j) -> int { return (j == 0) ? node : csr[p0 + j - 1]; };
    int k = 0;
    for (; k + 8 <= K; k += 8) {
        int i0 = idxAt(k + half);
        int i1 = csr[p0 + k + 1 + half];
        int i2 = csr[p0 + k + 3 + half];
        int i3 = csr[p0 + k + 5 + half];
        uint4 u0 = in[(size_t)i0 * 32 + fl];
        uint4 u1 = in[(size_t)i1 * 32 + fl];
        uint4 u2 = in[(size_t)i2 * 32 + fl];
        uint4 u3 = in[(size_t)i3 * 32 + fl];
        accum(u0); accum(u1); accum(u2); accum(u3);
    }
    for (; k + 2 <= K; k += 2) {
        accum(in[(size_t)idxAt(k + half) * 32 + fl]);
    }
    if (k < K && half == 0) {
        accum(in[(size_t)idxAt(k) * 32 + fl]);
    }
#define RED(v) v += __shfl_xor(v, 32);
    RED(a0) RED(a1) RED(a2) RED(a3) RED(a4) RED(a5) RED(a6) RED(a7)
#undef RED
    if (half == 0) {
        const float d = dinv[node];
        uint4 o;
        o.x = pk2(a0 * d, a1 * d); o.y = pk2(a2 * d, a3 * d);
        o.z = pk2(a4 * d, a5 * d); o.w = pk2(a6 * d, a7 * d);
        out[(size_t)node * 32 + fl] = o;
    }
}

// ---------------- final layer: 40-feat rows padded to 128 B (stride 64 bf16) + log_softmax ----------------
__global__ __launch_bounds__(256) void k_agg3(const uint4* __restrict__ T3b,
                                              const int* __restrict__ offs,
                                              const int* __restrict__ csr,
                                              const float* __restrict__ dinv,
                                              const float* __restrict__ b3,
                                              float* __restrict__ out) {
    const int lane = threadIdx.x & 63;
    const int grp = lane / 5;
    const int fl = lane - grp * 5;
    const bool act = grp < 12;
    const int node = blockIdx.x * 4 + (threadIdx.x >> 6);
    const int p0 = offs[node];
    const int K = offs[node + 1] - p0 + 1;
    float a0=0,a1=0,a2=0,a3=0,a4=0,a5=0,a6=0,a7=0;
    auto accum = [&](uint4 u) {
        a0 += bflo(u.x); a1 += bfhi(u.x);
        a2 += bflo(u.y); a3 += bfhi(u.y);
        a4 += bflo(u.z); a5 += bfhi(u.z);
        a6 += bflo(u.w); a7 += bfhi(u.w);
    };
    const char* Tb = (const char*)T3b;
    int k = 0;
    if (act) {
        for (; k + 12 <= K; k += 12) {
            int j = k + grp;
            int i0 = (j == 0) ? node : csr[p0 + j - 1];
            accum(*(const uint4*)(Tb + (size_t)i0 * 128 + fl * 16));
        }
        int rem = K - k;
        if (grp < rem) {
            int j = k + grp;
            int i0 = (j == 0) ? node : csr[p0 + j - 1];
            accum(*(const uint4*)(Tb + (size_t)i0 * 128 + fl * 16));
        }
    }
#define RED3(v) { float t = __shfl(v, lane + 30); v += t; t = __shfl(v, lane + 15); v += t; \
                  float u1 = __shfl(v, lane + 5); float u2 = __shfl(v, lane + 10); v += u1 + u2; }
    RED3(a0) RED3(a1) RED3(a2) RED3(a3) RED3(a4) RED3(a5) RED3(a6) RED3(a7)
#undef RED3
    const float d = dinv[node];
    float v[8];
    if (grp == 0) {
        const float4* bp = (const float4*)(b3 + fl * 8);
        float4 b01 = bp[0], b23 = bp[1];
        v[0] = a0 * d + b01.x; v[1] = a1 * d + b01.y;
        v[2] = a2 * d + b01.z; v[3] = a3 * d + b01.w;
        v[4] = a4 * d + b23.x; v[5] = a5 * d + b23.y;
        v[6] = a6 * d + b23.z; v[7] = a7 * d + b23.w;
    } else {
#pragma unroll
        for (int j = 0; j < 8; ++j) v[j] = -INFINITY;
    }
    float m = v[0];
#pragma unroll
    for (int j = 1; j < 8; ++j) m = fmaxf(m, v[j]);
    float mm = __shfl(m, 0);
#pragma unroll
    for (int l = 1; l < 5; ++l) mm = fmaxf(mm, __shfl(m, l));
    float e = 0.f;
    if (grp == 0) {
#pragma unroll
        for (int j = 0; j < 8; ++j) e += __expf(v[j] - mm);
    }
    float s = __shfl(e, 0);
#pragma unroll
    for (int l = 1; l < 5; ++l) s += __shfl(e, l);
    float ls = __logf(s);
    if (grp == 0) {
        float* op = out + (size_t)node * 40 + fl * 8;
        float4 o0 = {v[0] - mm - ls, v[1] - mm - ls, v[2] - mm - ls, v[3] - mm - ls};
        float4 o1 = {v[4] - mm - ls, v[5] - mm - ls, v[6] - mm - ls, v[7] - mm - ls};
        *(float4*)op = o0;
        *(float4*)(op + 4) = o1;
    }
}

// ---------------- MFMA GEMM: whole 64-row A tile staged to LDS ONCE (single barrier),
// ---------------- padded LDS rows (conflict-free ds_read_b128), BN+ReLU once at staging,
// ---------------- dinv prescale on C, optional fused column stats + BN finalize ----------------
template <int K, int WNB, bool PRESCALE, bool BNA, bool STATS>
__global__ __launch_bounds__(256) void k_gemm(const __hip_bfloat16* __restrict__ A,
                                              const __hip_bfloat16* __restrict__ Wswz,
                                              const float* __restrict__ dinvp,
                                              const float* __restrict__ bnsc,
                                              const float* __restrict__ bnsh,
                                              unsigned short* __restrict__ Cout,
                                              int M, int NOUT, int CS,
                                              float* __restrict__ sums,
                                              float* __restrict__ sq,
                                              const float* __restrict__ gamma,
                                              const float* __restrict__ beta,
                                              float* __restrict__ scale,
                                              float* __restrict__ shift,
                                              int* __restrict__ done) {
    constexpr int KSTEPS = K / 32;
    constexpr int LROW   = K + 8;          // bf16 per LDS row: +16B pad -> bank stride 4 (mod 32)
    constexpr int U4R    = K / 8;          // uint4 per A row
    constexpr int NU     = K / 32;         // uint4 staged per thread (64 rows * U4R / 256)
    constexpr int RPU    = 256 / U4R;      // rows advanced per staging step
    __shared__ __align__(16) unsigned short As[64 * LROW];

    const int t = threadIdx.x;
    const int lane = t & 63;
    const int wid  = t >> 6;
    const int wn = wid * (WNB * 16);
    const long rowBase = (long)blockIdx.x * 64;
    const int cl = lane & 15, q = lane >> 4;

    // ---- stage whole A tile (64 x K bf16), fully parallel loads, one barrier ----
    const int cst = t % U4R;               // uint4 col within row
    const int r0l = t / U4R;               // starting local row
    f32x2 cp[4], hp[4];
    if constexpr (BNA) {
        const f32x2* cpp = (const f32x2*)(bnsc + cst * 8);
        const f32x2* hpp = (const f32x2*)(bnsh + cst * 8);
#pragma unroll
        for (int j = 0; j < 4; ++j) { cp[j] = cpp[j]; hp[j] = hpp[j]; }
    }
    uint4 stg[NU];
#pragma unroll
    for (int u = 0; u < NU; ++u) {
        int rl = r0l + u * RPU;
        stg[u] = *(const uint4*)((const char*)A + (size_t)(rowBase + rl) * (K * 2) + (size_t)cst * 16);
    }
#pragma unroll
    for (int u = 0; u < NU; ++u) {
        uint4 v = stg[u];
        if constexpr (BNA) {
            v.x = bnrelu_pk(v.x, cp[0], hp[0]);
            v.y = bnrelu_pk(v.y, cp[1], hp[1]);
            v.z = bnrelu_pk(v.z, cp[2], hp[2]);
            v.w = bnrelu_pk(v.w, cp[3], hp[3]);
        }
        int rl = r0l + u * RPU;
        *(uint4*)&As[rl * LROW + cst * 8] = v;
    }
    __syncthreads();

    const __hip_bfloat16* bptr[WNB];
#pragma unroll
    for (int nf = 0; nf < WNB; ++nf)
        bptr[nf] = Wswz + (size_t)(wn / 16 + nf) * KSTEPS * 512 + (size_t)lane * 8;

    f32x4 acc[4][WNB];
    const f32x4 z = {0.f, 0.f, 0.f, 0.f};
#pragma unroll
    for (int mf = 0; mf < 4; ++mf)
#pragma unroll
        for (int nf = 0; nf < WNB; ++nf) acc[mf][nf] = z;

#pragma unroll
    for (int ks = 0; ks < KSTEPS; ++ks) {
        bf16x8 a[4], b[WNB];
#pragma unroll
        for (int nf = 0; nf < WNB; ++nf)
            b[nf] = __builtin_bit_cast(bf16x8, *(const uint4*)(bptr[nf] + ks * 512));
#pragma unroll
        for (int mf = 0; mf < 4; ++mf)
            a[mf] = __builtin_bit_cast(bf16x8, *(const uint4*)&As[(mf * 16 + cl) * LROW + ks * 32 + q * 8]);
#pragma unroll
        for (int mf = 0; mf < 4; ++mf)
#pragma unroll
            for (int nf = 0; nf < WNB; ++nf)
                acc[mf][nf] = __builtin_amdgcn_mfma_f32_16x16x32_bf16(a[mf], b[nf], acc[mf][nf], 0, 0, 0);
    }

#pragma unroll
    for (int mf = 0; mf < 4; ++mf)
#pragma unroll
        for (int i = 0; i < 4; ++i) {
            long row = rowBase + mf * 16 + q * 4 + i;
            if (row >= M) continue;
            float dv = PRESCALE ? dinvp[row] : 1.0f;
#pragma unroll
            for (int nf = 0; nf < WNB; ++nf) {
                int col = wn + nf * 16 + cl;
                if (col < NOUT)
                    Cout[row * CS + col] = f2b(PRESCALE ? acc[mf][nf][i] * dv : acc[mf][nf][i]);
            }
        }

    if constexpr (STATS) {
        // per-column partial sums over this block's 64 rows (M % 64 == 0)
#pragma unroll
        for (int nf = 0; nf < WNB; ++nf) {
            float s = 0.f, s2 = 0.f;
#pragma unroll
            for (int mf = 0; mf < 4; ++mf)
#pragma unroll
                for (int i = 0; i < 4; ++i) {
                    long row = rowBase + mf * 16 + q * 4 + i;
                    float v = (row < M) ? acc[mf][nf][i] : 0.f;
                    s += v; s2 += v * v;
                }
            s  += __shfl_xor(s, 16);  s  += __shfl_xor(s, 32);
            s2 += __shfl_xor(s2, 16); s2 += __shfl_xor(s2, 32);
            if (q == 0) {
                int col = wn + nf * 16 + cl;
                if (col < NOUT) {
                    atomicAdd(&sums[col], s);
                    atomicAdd(&sq[col], s2);
                }
            }
        }
        __syncthreads();                       // drains this block's atomics before done
        __shared__ int lastf;
        if (threadIdx.x == 0) lastf = (atomicAdd(done, 1) == (int)gridDim.x - 1) ? 1 : 0;
        __syncthreads();
        if (lastf) {
            const int tt = threadIdx.x;        // 256 threads
            float su = atomicAdd(&sums[tt], 0.0f);   // L2-coherent read
            float qu = atomicAdd(&sq[tt], 0.0f);
            float mu = su * (1.0f / NNODES);
            float var = qu * (1.0f / NNODES) - mu * mu;
            if (var < 0.f) var = 0.f;
            float sc = gamma[tt] * rsqrtf(var + EPS);
            scale[tt] = sc;
            shift[tt] = beta[tt] - mu * sc;
        }
    }
}

// ---------------- BN stats over bf16 matrix, vectorized + done-counter finalize ----------------
__global__ __launch_bounds__(256) void k_stats(const uint4* __restrict__ Zu,
                                               float* __restrict__ sums, float* __restrict__ sq,
                                               const float* __restrict__ gamma,
                                               const float* __restrict__ beta,
                                               float* __restrict__ scale, float* __restrict__ shift,
                                               int* __restrict__ done) {
    __shared__ float reds[8][256];
    __shared__ float redq[8][256];
    const int t = threadIdx.x;
    const int cg = t & 31;        // col group: cols cg*8 .. cg*8+7
    const int rs = t >> 5;        // row slice: rows rs*32 .. rs*32+31 of this block's 256
    const long r0 = (long)blockIdx.x * 256 + (long)rs * 32;
    float s[8], q[8];
#pragma unroll
    for (int j = 0; j < 8; ++j) { s[j] = 0.f; q[j] = 0.f; }
    for (int i = 0; i < 32; ++i) {
        long r = r0 + i;
        if (r >= NNODES) break;
        uint4 u = Zu[r * 32 + cg];
        float v0 = bflo(u.x), v1 = bfhi(u.x), v2 = bflo(u.y), v3 = bfhi(u.y);
        float v4 = bflo(u.z), v5 = bfhi(u.z), v6 = bflo(u.w), v7 = bfhi(u.w);
        s[0] += v0; q[0] += v0 * v0;  s[1] += v1; q[1] += v1 * v1;
        s[2] += v2; q[2] += v2 * v2;  s[3] += v3; q[3] += v3 * v3;
        s[4] += v4; q[4] += v4 * v4;  s[5] += v5; q[5] += v5 * v5;
        s[6] += v6; q[6] += v6 * v6;  s[7] += v7; q[7] += v7 * v7;
    }
#pragma unroll
    for (int j = 0; j < 8; ++j) {
        reds[rs][cg * 8 + j] = s[j];
        redq[rs][cg * 8 + j] = q[j];
    }
    __syncthreads();
    float S = 0.f, Q = 0.f;
#pragma unroll
    for (int j = 0; j < 8; ++j) { S += reds[j][t]; Q += redq[j][t]; }
    atomicAdd(&sums[t], S);
    atomicAdd(&sq[t], Q);
    __syncthreads();                       // drains this block's atomics before done
    __shared__ int lastf;
    if (t == 0) lastf = (atomicAdd(done, 1) == (int)gridDim.x - 1) ? 1 : 0;
    __syncthreads();
    if (lastf) {
        float su = atomicAdd(&sums[t], 0.0f);
        float qu = atomicAdd(&sq[t], 0.0f);
        float mu = su * (1.0f / NNODES);
        float var = qu * (1.0f / NNODES) - mu * mu;
        if (var < 0.f) var = 0.f;
        float sc = gamma[t] * rsqrtf(var + EPS);
        scale[t] = sc;
        shift[t] = beta[t] - mu * sc;
    }
}

// ---------------- driver ----------------
extern "C" void kernel_launch(void* const* d_in, const int* in_sizes, int n_in,
                              void* d_out, int out_size, void* d_ws, size_t ws_size,
                              hipStream_t stream) {
    const float* x   = (const float*)d_in[0];
    const int*   ei  = (const int*)d_in[1];
    const float* W1  = (const float*)d_in[2];
    const float* g1  = (const float*)d_in[4];
    const float* be1 = (const float*)d_in[5];
    const float* W2  = (const float*)d_in[6];
    const float* g2  = (const float*)d_in[8];
    const float* be2 = (const float*)d_in[9];
    const float* W3  = (const float*)d_in[10];
    const float* b3  = (const float*)d_in[11];
    // b1 (d_in[3]) and b2 (d_in[7]) cancel exactly under BatchNorm — skipped.

    char* w = (char*)d_ws;
    size_t o = 0;
    auto alloc = [&](size_t b) { size_t r = o; o += (b + 255) & ~(size_t)255; return r; };
    int*   offs = (int*)(w + alloc((size_t)(NNODES + 1) * 4));
    float* dinv = (float*)(w + alloc((size_t)NNODES * 4));
    int*   cnt  = (int*)(w + alloc((size_t)NEB * NBUCK * 4));   // 1.6 MB
    int*   btot = (int*)(w + alloc(NBUCK * 4));
    int*   bbase= (int*)(w + alloc((NBUCK + 1) * 4));
    unsigned* ebuf = (unsigned*)(w + alloc((size_t)NEDGES * 4));
    int*   csr  = (int*)(w + alloc((size_t)NEDGES * 4));
    float* stats = (float*)(w + alloc(4 * 256 * 4 + 32));       // sums1,sq1,sums2,sq2,done1,done2
    float* bnp   = (float*)(w + alloc(4 * 256 * 4));            // scale1,shift1,scale2,shift2
    unsigned short* w1s = (unsigned short*)(w + alloc(65536));
    unsigned short* w2s = (unsigned short*)(w + alloc(131072));
    unsigned short* w3s = (unsigned short*)(w + alloc(32768));  // 4 col-groups (4th zeroed)
    __hip_bfloat16* xb   = (__hip_bfloat16*)(w + alloc((size_t)NNODES * 128 * 2));
    __hip_bfloat16* buf0 = (__hip_bfloat16*)(w + alloc((size_t)NNODES * 128 * 2)); // y0 -> T3' (stride 64)
    __hip_bfloat16* buf1 = (__hip_bfloat16*)(w + alloc((size_t)NNODES * 256 * 2)); // Z1 -> Z2
    __hip_bfloat16* buf2 = (__hip_bfloat16*)(w + alloc((size_t)NNODES * 256 * 2)); // y2'

    float* sums1 = stats;       float* sq1 = stats + 256;
    float* sums2 = stats + 512; float* sq2 = stats + 768;
    int*   done1 = (int*)(stats + 1024);
    int*   done2 = done1 + 1;
    float* scale1 = bnp;        float* shift1 = bnp + 256;
    float* scale2 = bnp + 512;  float* shift2 = bnp + 768;

    const int SB = (NNODES + 255) / 256;  // 782
    const int GB = NNODES / 64;           // 3125 gemm blocks (200000 % 64 == 0)

    // CSR build + fused weight swizzle + stats zeroing (no memset dispatch)
    k_cnt<<<NEB + 57, 256, 0, stream>>>(ei, cnt, W1, W2, W3, w1s, w2s, w3s, (unsigned*)stats);
    k_bscan<<<(NBUCK * 64 + 255) / 256, 256, 0, stream>>>(cnt, btot);
    k_place<<<NEB, 256, 0, stream>>>(ei, ei + NEDGES, cnt, btot, bbase, ebuf);
    k_sort2<<<NBUCK, 256, 0, stream>>>(ebuf, bbase, offs, dinv, csr, x, (uint4*)xb);

    // layer 1: BN1 stats fused into GEMM epilogue, finalized by last block (done-counter);
    // aggf split into 2 node-range chunks (diagnostic: keeps top-5 informative)
    for (int c = 0; c < 2; ++c)
        k_aggf<<<AGGF_CHUNK / 4, 256, 0, stream>>>((const uint4*)xb, offs, csr, dinv, (uint4*)buf0, c * AGGF_CHUNK);
    k_gemm<128, 4, false, false, true><<<GB, 256, 0, stream>>>(buf0, (const __hip_bfloat16*)w1s, nullptr, nullptr, nullptr, (unsigned short*)buf1, NNODES, 256, 256, sums1, sq1, g1, be1, scale1, shift1, done1);

    // layer 2: gemm2 applies BN1+ReLU once at LDS staging, prescales C by dinv;
    // aggb split into 4 node-range chunks (diagnostic)
    k_gemm<256, 4, true, true, false><<<GB, 256, 0, stream>>>(buf1, (const __hip_bfloat16*)w2s, dinv, scale1, shift1, (unsigned short*)buf2, NNODES, 256, 256, nullptr, nullptr, nullptr, nullptr, nullptr, nullptr, nullptr);
    for (int c = 0; c < 4; ++c)
        k_aggb<<<AGGB_CHUNK / 4, 256, 0, stream>>>((const uint4*)buf2, offs, csr, dinv, (uint4*)buf1, c * AGGB_CHUNK);
    k_stats<<<SB, 256, 0, stream>>>((const uint4*)buf1, sums2, sq2, g2, be2, scale2, shift2, done2);

    // layer 3: gemm3 applies BN2+ReLU once at LDS staging, prescales C by dinv, writes 128B-padded rows;
    // then fused agg+softmax reads exactly one cache line per gathered row
    k_gemm<256, 1, true, true, false><<<GB, 256, 0, stream>>>(buf1, (const __hip_bfloat16*)w3s, dinv, scale2, shift2, (unsigned short*)buf0, NNODES, 40, 64, nullptr, nullptr, nullptr, nullptr, nullptr, nullptr, nullptr);
    k_agg3<<<NNODES / 4, 256, 0, stream>>>((const uint4*)buf0, offs, csr, dinv, b3, (float*)d_out);
}

// Round 11
// 937.435 us; speedup vs baseline: 1.1111x; 1.0774x over previous
//
#include <hip/hip_runtime.h>
#include <hip/hip_bf16.h>

#define NNODES 200000
#define NEDGES 3200000
#define NBUCK 782            // ceil(NNODES/256)
#define NEB 512              // edge blocks for counting sort
#define EPB (NEDGES / NEB)   // 6250 edges per block
#define EPS 1e-5f
#define AGGB_CHUNK 50000     // nodes per aggb chunk (4 chunks) — diagnostic split
#define AGGF_CHUNK 100000    // nodes per aggf chunk (2 chunks) — diagnostic split
#define NREP 16              // stats accumulator replicas (kills hot-address atomic queueing)

typedef __bf16 bf16x8 __attribute__((ext_vector_type(8)));
typedef float  f32x4  __attribute__((ext_vector_type(4)));
typedef float  f32x2  __attribute__((ext_vector_type(2)));

__device__ __forceinline__ float bflo(unsigned u) { return __uint_as_float(u << 16); }
__device__ __forceinline__ float bfhi(unsigned u) { return __uint_as_float(u & 0xffff0000u); }
__device__ __forceinline__ unsigned short f2b(float f) {
    return __builtin_bit_cast(unsigned short, __float2bfloat16(f));
}
__device__ __forceinline__ unsigned pk2(float a, float b) {
    return (unsigned)f2b(a) | ((unsigned)f2b(b) << 16);
}
// BN+ReLU on a packed bf16 pair, using packed f32 math (v_pk_fma_f32 / v_pk_max_f32)
__device__ __forceinline__ unsigned bnrelu_pk(unsigned u, f32x2 c, f32x2 h) {
    f32x2 v = { __uint_as_float(u << 16), __uint_as_float(u & 0xffff0000u) };
    v = __builtin_elementwise_fma(v, c, h);
    const f32x2 z = {0.f, 0.f};
    v = __builtin_elementwise_max(v, z);
    return pk2(v[0], v[1]);
}

// ---------------- weight swizzle helper ----------------
__device__ __forceinline__ void prepw_one(const float* __restrict__ W,
                                          unsigned short* __restrict__ Wswz,
                                          int K, int NOUT, int t) {
    int KSTEPS = K / 32;
    int lane = t & 63;
    int ks = (t >> 6) % KSTEPS;
    int g  = (t >> 6) / KSTEPS;
    int c = lane & 15, q = lane >> 4;
    int col = g * 16 + c;
    int k0 = ks * 32 + q * 8;
    unsigned short vals[8];
#pragma unroll
    for (int j = 0; j < 8; ++j)
        vals[j] = (col < NOUT) ? f2b(W[(size_t)(k0 + j) * NOUT + col]) : (unsigned short)0;
    *(uint4*)((char*)Wswz + (size_t)t * 16) = __builtin_bit_cast(uint4, vals);
}

// ---------------- CSR build step 1: per-block bucket histogram
// ----------------  + fused weight swizzle + stats zeroing (independent blocks) ----------------
__global__ __launch_bounds__(256) void k_cnt(const int* __restrict__ row, int* __restrict__ cnt,
                                             const float* __restrict__ W1,
                                             const float* __restrict__ W2,
                                             const float* __restrict__ W3,
                                             unsigned short* __restrict__ w1s,
                                             unsigned short* __restrict__ w2s,
                                             unsigned short* __restrict__ w3s,
                                             unsigned* __restrict__ statsz) {
    const int blk = blockIdx.x;
    if (blk >= NEB + 56) {                       // zero replicated stats + done counters
        const int zid = blk - (NEB + 56);        // 8 zero blocks
        for (int i = zid * 256 + threadIdx.x; i < 2 * NREP * 512 + 2; i += 8 * 256)
            statsz[i] = 0u;
        return;
    }
    if (blk >= NEB) {                            // weight swizzle: 56 blocks = 14336 threads
        int t = (blk - NEB) * 256 + threadIdx.x;
        if (t < 4096) prepw_one(W1, w1s, 128, 256, t);
        else if (t < 12288) prepw_one(W2, w2s, 256, 256, t - 4096);
        else if (t < 14336) prepw_one(W3, w3s, 256, 40, t - 12288);   // 4 col-groups, zero-padded
        return;
    }
    __shared__ int h[NBUCK];
    for (int i = threadIdx.x; i < NBUCK; i += 256) h[i] = 0;
    __syncthreads();
    const int e0 = blk * EPB;
    for (int i = e0 + threadIdx.x; i < e0 + EPB; i += 256)
        atomicAdd(&h[row[i] >> 8], 1);
    __syncthreads();
    for (int i = threadIdx.x; i < NBUCK; i += 256)
        cnt[(size_t)blk * NBUCK + i] = h[i];
}

__global__ __launch_bounds__(256) void k_bscan(int* __restrict__ cnt, int* __restrict__ btot) {
    const int wv = (blockIdx.x * 256 + threadIdx.x) >> 6;   // bucket
    const int lane = threadIdx.x & 63;
    if (wv >= NBUCK) return;
    int v[8]; int s = 0;
#pragma unroll
    for (int j = 0; j < 8; ++j) {
        v[j] = cnt[(size_t)(lane * 8 + j) * NBUCK + wv];
        s += v[j];
    }
    int excl = s;
#pragma unroll
    for (int o = 1; o < 64; o <<= 1) {
        int t = __shfl_up(excl, o);
        if (lane >= o) excl += t;
    }
    excl -= s;
    if (lane == 63) btot[wv] = excl + s;
    int base = excl;
#pragma unroll
    for (int j = 0; j < 8; ++j) {
        int t = v[j];
        cnt[(size_t)(lane * 8 + j) * NBUCK + wv] = base;
        base += t;
    }
}

// ---------------- place: in-block scan of btot (replaces k_btscan) + scatter ----------------
__global__ __launch_bounds__(256) void k_place(const int* __restrict__ row, const int* __restrict__ col,
                                               const int* __restrict__ cnt, const int* __restrict__ btot,
                                               int* __restrict__ bbase, unsigned* __restrict__ ebuf) {
    __shared__ int sbb[NBUCK];
    __shared__ int tp[256];
    __shared__ int base[NBUCK];
    const int t = threadIdx.x;
    // chunked exclusive scan of btot[0..NBUCK): thread t owns [t*4, t*4+4)
    int v[4]; int loc = 0;
    const int i0 = t * 4;
#pragma unroll
    for (int j = 0; j < 4; ++j) {
        int idx = i0 + j;
        v[j] = (idx < NBUCK) ? btot[idx] : 0;
        loc += v[j];
    }
    tp[t] = loc;
    __syncthreads();
    for (int off = 1; off < 256; off <<= 1) {
        int u = (t >= off) ? tp[t - off] : 0;
        __syncthreads();
        tp[t] += u;
        __syncthreads();
    }
    int run = tp[t] - loc;   // exclusive prefix of this thread's chunk
#pragma unroll
    for (int j = 0; j < 4; ++j) {
        int idx = i0 + j;
        if (idx < NBUCK) sbb[idx] = run;
        run += v[j];
    }
    __syncthreads();
    if (blockIdx.x == 0) {   // publish for k_sort2
        for (int i = t; i < NBUCK; i += 256) bbase[i] = sbb[i];
        if (t == 0) bbase[NBUCK] = NEDGES;
    }
    for (int i = t; i < NBUCK; i += 256)
        base[i] = sbb[i] + cnt[(size_t)blockIdx.x * NBUCK + i];
    __syncthreads();
    const int e0 = blockIdx.x * EPB;
    for (int i = e0 + t; i < e0 + EPB; i += 256) {
        int r = row[i], c = col[i];
        int p = atomicAdd(&base[r >> 8], 1);
        ebuf[p] = ((unsigned)(r & 255) << 18) | (unsigned)c;   // col < 2^18
    }
}

// fused: per-bucket degree count -> offs/dinv -> rank -> final CSR -> x cast (uses fresh dinv)
__global__ __launch_bounds__(256) void k_sort2(const unsigned* __restrict__ ebuf,
                                               const int* __restrict__ bbase,
                                               int* __restrict__ offs, float* __restrict__ dinv,
                                               int* __restrict__ csr,
                                               const float* __restrict__ x,
                                               uint4* __restrict__ xb) {
    __shared__ int cnt[256];
    __shared__ int sofs[256];
    __shared__ int sc[256];
    __shared__ float sdinv[256];
    const int b = blockIdx.x;
    const int t = threadIdx.x;
    const int n0 = b * 256;
    cnt[t] = 0;
    __syncthreads();
    const int s = bbase[b], e = bbase[b + 1];
    for (int i = s + t; i < e; i += 256)
        atomicAdd(&cnt[ebuf[i] >> 18], 1);
    __syncthreads();
    const int c = cnt[t];
    sc[t] = c;
    __syncthreads();
    for (int off = 1; off < 256; off <<= 1) {
        int v = (t >= off) ? sc[t - off] : 0;
        __syncthreads();
        sc[t] += v;
        __syncthreads();
    }
    const int excl = sc[t] - c;
    sofs[t] = s + excl;
    const int n = n0 + t;
    float dv = rsqrtf((float)(c + 1));
    sdinv[t] = dv;
    if (n < NNODES) {
        offs[n] = s + excl;
        dinv[n] = dv;
    }
    if (b == NBUCK - 1 && t == 0) offs[NNODES] = NEDGES;
    cnt[t] = 0;
    __syncthreads();
    for (int i = s + t; i < e; i += 256) {
        unsigned v = ebuf[i];
        int nl = v >> 18;
        int rank = atomicAdd(&cnt[nl], 1);
        csr[sofs[nl] + rank] = (int)(v & 0x3FFFFu);
    }
    // fused x -> prescaled bf16 cast for this block's nodes (coalesced 128 KB read)
    const int nn = (NNODES - n0 < 256) ? (NNODES - n0) : 256;
    const float4* xp = (const float4*)(x + (size_t)n0 * 128);
    uint4* xo = xb + (size_t)n0 * 16;
    const int lim = nn * 16;
    for (int i = t; i < lim; i += 256) {
        float d = sdinv[i >> 4];
        float4 a = xp[i * 2], bb = xp[i * 2 + 1];
        uint4 o;
        o.x = pk2(a.x * d, a.y * d);  o.y = pk2(a.z * d, a.w * d);
        o.z = pk2(bb.x * d, bb.y * d); o.w = pk2(bb.z * d, bb.w * d);
        xo[i] = o;
    }
}

// ---------------- aggregation: F=128 rows (16 x uint4), up to 16 edges in flight,
// ---------------- node-range chunked (diagnostic split; nodes independent) ----------------
__global__ __launch_bounds__(256) void k_aggf(const uint4* __restrict__ in,
                                              const int* __restrict__ offs,
                                              const int* __restrict__ csr,
                                              const float* __restrict__ dinv,
                                              uint4* __restrict__ out,
                                              int nbase) {
    const int lane = threadIdx.x & 63;
    const int grp = lane >> 4;
    const int fl = lane & 15;
    const int node = nbase + blockIdx.x * 4 + (threadIdx.x >> 6);
    const int p0 = offs[node];
    const int K = offs[node + 1] - p0 + 1;   // +1 virtual self item at k=0
    float a0=0,a1=0,a2=0,a3=0,a4=0,a5=0,a6=0,a7=0;
    auto accum = [&](uint4 u) {
        a0 += bflo(u.x); a1 += bfhi(u.x);
        a2 += bflo(u.y); a3 += bfhi(u.y);
        a4 += bflo(u.z); a5 += bfhi(u.z);
        a6 += bflo(u.w); a7 += bfhi(u.w);
    };
    int k = 0;
    for (; k + 16 <= K; k += 16) {
        int j0 = k + grp;
        int i0 = (j0 == 0) ? node : csr[p0 + j0 - 1];
        int i1 = csr[p0 + k + 3 + grp];
        int i2 = csr[p0 + k + 7 + grp];
        int i3 = csr[p0 + k + 11 + grp];
        uint4 u0 = in[(size_t)i0 * 16 + fl];
        uint4 u1 = in[(size_t)i1 * 16 + fl];
        uint4 u2 = in[(size_t)i2 * 16 + fl];
        uint4 u3 = in[(size_t)i3 * 16 + fl];
        accum(u0); accum(u1); accum(u2); accum(u3);
    }
    for (; k + 8 <= K; k += 8) {
        int j0 = k + grp;
        int i0 = (j0 == 0) ? node : csr[p0 + j0 - 1];
        int i1 = csr[p0 + k + 3 + grp];
        uint4 u0 = in[(size_t)i0 * 16 + fl];
        uint4 u1 = in[(size_t)i1 * 16 + fl];
        accum(u0); accum(u1);
    }
    for (; k + 4 <= K; k += 4) {
        int j0 = k + grp;
        int i0 = (j0 == 0) ? node : csr[p0 + j0 - 1];
        accum(in[(size_t)i0 * 16 + fl]);
    }
    int rem = K - k;
    if (grp < rem) {
        int j0 = k + grp;
        int i0 = (j0 == 0) ? node : csr[p0 + j0 - 1];
        accum(in[(size_t)i0 * 16 + fl]);
    }
#define RED(v) v += __shfl_xor(v, 32); v += __shfl_xor(v, 16);
    RED(a0) RED(a1) RED(a2) RED(a3) RED(a4) RED(a5) RED(a6) RED(a7)
#undef RED
    if (grp == 0) {
        const float d = dinv[node];
        uint4 o;
        o.x = pk2(a0 * d, a1 * d); o.y = pk2(a2 * d, a3 * d);
        o.z = pk2(a4 * d, a5 * d); o.w = pk2(a6 * d, a7 * d);
        out[(size_t)node * 16 + fl] = o;
    }
}

// ---------------- aggregation: F=256 rows (32 x uint4), 2 edges per load, unroll 4,
// ---------------- node-range chunked (diagnostic split; nodes independent) ----------------
__global__ __launch_bounds__(256) void k_aggb(const uint4* __restrict__ in,
                                              const int* __restrict__ offs,
                                              const int* __restrict__ csr,
                                              const float* __restrict__ dinv,
                                              uint4* __restrict__ out,
                                              int nbase) {
    const int lane = threadIdx.x & 63;
    const int half = lane >> 5;
    const int fl = lane & 31;
    const int node = nbase + blockIdx.x * 4 + (threadIdx.x >> 6);
    const int p0 = offs[node];
    const int K = offs[node + 1] - p0 + 1;
    float a0=0,a1=0,a2=0,a3=0,a4=0,a5=0,a6=0,a7=0;
    auto accum = [&](uint4 u) {
        a0 += bflo(u.x); a1 += bfhi(u.x);
        a2 += bflo(u.y); a3 += bfhi(u.y);
        a4 += bflo(u.z); a5 += bfhi(u.z);
        a6 += bflo(u.w); a7 += bfhi(u.w);
    };
    auto idxAt = [&](int j) -> int { return (j == 0) ? node : csr[p0 + j - 1]; };
    int k = 0;
    for (; k + 8 <= K; k += 8) {
        int i0 = idxAt(k + half);
        int i1 = csr[p0 + k + 1 + half];
        int i2 = csr[p0 + k + 3 + half];
        int i3 = csr[p0 + k + 5 + half];
        uint4 u0 = in[(size_t)i0 * 32 + fl];
        uint4 u1 = in[(size_t)i1 * 32 + fl];
        uint4 u2 = in[(size_t)i2 * 32 + fl];
        uint4 u3 = in[(size_t)i3 * 32 + fl];
        accum(u0); accum(u1); accum(u2); accum(u3);
    }
    for (; k + 2 <= K; k += 2) {
        accum(in[(size_t)idxAt(k + half) * 32 + fl]);
    }
    if (k < K && half == 0) {
        accum(in[(size_t)idxAt(k) * 32 + fl]);
    }
#define RED(v) v += __shfl_xor(v, 32);
    RED(a0) RED(a1) RED(a2) RED(a3) RED(a4) RED(a5) RED(a6) RED(a7)
#undef RED
    if (half == 0) {
        const float d = dinv[node];
        uint4 o;
        o.x = pk2(a0 * d, a1 * d); o.y = pk2(a2 * d, a3 * d);
        o.z = pk2(a4 * d, a5 * d); o.w = pk2(a6 * d, a7 * d);
        out[(size_t)node * 32 + fl] = o;
    }
}

// ---------------- final layer: 40-feat rows padded to 128 B (stride 64 bf16) + log_softmax ----------------
__global__ __launch_bounds__(256) void k_agg3(const uint4* __restrict__ T3b,
                                              const int* __restrict__ offs,
                                              const int* __restrict__ csr,
                                              const float* __restrict__ dinv,
                                              const float* __restrict__ b3,
                                              float* __restrict__ out) {
    const int lane = threadIdx.x & 63;
    const int grp = lane / 5;
    const int fl = lane - grp * 5;
    const bool act = grp < 12;
    const int node = blockIdx.x * 4 + (threadIdx.x >> 6);
    const int p0 = offs[node];
    const int K = offs[node + 1] - p0 + 1;
    float a0=0,a1=0,a2=0,a3=0,a4=0,a5=0,a6=0,a7=0;
    auto accum = [&](uint4 u) {
        a0 += bflo(u.x); a1 += bfhi(u.x);
        a2 += bflo(u.y); a3 += bfhi(u.y);
        a4 += bflo(u.z); a5 += bfhi(u.z);
        a6 += bflo(u.w); a7 += bfhi(u.w);
    };
    const char* Tb = (const char*)T3b;
    int k = 0;
    if (act) {
        for (; k + 12 <= K; k += 12) {
            int j = k + grp;
            int i0 = (j == 0) ? node : csr[p0 + j - 1];
            accum(*(const uint4*)(Tb + (size_t)i0 * 128 + fl * 16));
        }
        int rem = K - k;
        if (grp < rem) {
            int j = k + grp;
            int i0 = (j == 0) ? node : csr[p0 + j - 1];
            accum(*(const uint4*)(Tb + (size_t)i0 * 128 + fl * 16));
        }
    }
#define RED3(v) { float t = __shfl(v, lane + 30); v += t; t = __shfl(v, lane + 15); v += t; \
                  float u1 = __shfl(v, lane + 5); float u2 = __shfl(v, lane + 10); v += u1 + u2; }
    RED3(a0) RED3(a1) RED3(a2) RED3(a3) RED3(a4) RED3(a5) RED3(a6) RED3(a7)
#undef RED3
    const float d = dinv[node];
    float v[8];
    if (grp == 0) {
        const float4* bp = (const float4*)(b3 + fl * 8);
        float4 b01 = bp[0], b23 = bp[1];
        v[0] = a0 * d + b01.x; v[1] = a1 * d + b01.y;
        v[2] = a2 * d + b01.z; v[3] = a3 * d + b01.w;
        v[4] = a4 * d + b23.x; v[5] = a5 * d + b23.y;
        v[6] = a6 * d + b23.z; v[7] = a7 * d + b23.w;
    } else {
#pragma unroll
        for (int j = 0; j < 8; ++j) v[j] = -INFINITY;
    }
    float m = v[0];
#pragma unroll
    for (int j = 1; j < 8; ++j) m = fmaxf(m, v[j]);
    float mm = __shfl(m, 0);
#pragma unroll
    for (int l = 1; l < 5; ++l) mm = fmaxf(mm, __shfl(m, l));
    float e = 0.f;
    if (grp == 0) {
#pragma unroll
        for (int j = 0; j < 8; ++j) e += __expf(v[j] - mm);
    }
    float s = __shfl(e, 0);
#pragma unroll
    for (int l = 1; l < 5; ++l) s += __shfl(e, l);
    float ls = __logf(s);
    if (grp == 0) {
        float* op = out + (size_t)node * 40 + fl * 8;
        float4 o0 = {v[0] - mm - ls, v[1] - mm - ls, v[2] - mm - ls, v[3] - mm - ls};
        float4 o1 = {v[4] - mm - ls, v[5] - mm - ls, v[6] - mm - ls, v[7] - mm - ls};
        *(float4*)op = o0;
        *(float4*)(op + 4) = o1;
    }
}

// ---------------- MFMA GEMM: whole 64-row A tile staged to LDS once, BN+ReLU at staging,
// ---------------- LDS-transposed COALESCED uint4 C-store, dinv prescale,
// ---------------- replicated fused stats + BN finalize (done-counter) ----------------
template <int K, int WNB, int CS, bool PRESCALE, bool BNA, bool STATS>
__global__ __launch_bounds__(256) void k_gemm(const __hip_bfloat16* __restrict__ A,
                                              const __hip_bfloat16* __restrict__ Wswz,
                                              const float* __restrict__ dinvp,
                                              const float* __restrict__ bnsc,
                                              const float* __restrict__ bnsh,
                                              unsigned short* __restrict__ Cout,
                                              int M, int NOUT,
                                              float* __restrict__ statr,
                                              const float* __restrict__ gamma,
                                              const float* __restrict__ beta,
                                              float* __restrict__ scale,
                                              float* __restrict__ shift,
                                              int* __restrict__ done) {
    constexpr int KSTEPS = K / 32;
    constexpr int LROW   = K + 8;            // bf16 per A-LDS row (+16B pad)
    constexpr int U4R    = K / 8;            // uint4 per A row
    constexpr int NU     = K / 32;           // uint4 staged per thread
    constexpr int RPU    = 256 / U4R;        // rows advanced per staging step
    constexpr int LROWC  = CS + 16;          // bf16 per C-LDS row: +32B pad -> row stride ≡8 dwords mod 32
    constexpr int ABYTES = 64 * LROW * 2;
    constexpr int CBYTES = 64 * LROWC * 2;
    constexpr int SBYTES = (ABYTES > CBYTES) ? ABYTES : CBYTES;
    __shared__ __align__(16) char smem[SBYTES];
    unsigned short* As = (unsigned short*)smem;
    unsigned short* Ct = (unsigned short*)smem;   // union: Ct used after compute

    const int t = threadIdx.x;
    const int lane = t & 63;
    const int wid  = t >> 6;
    const int wn = wid * (WNB * 16);
    const long rowBase = (long)blockIdx.x * 64;
    const int cl = lane & 15, q = lane >> 4;

    // ---- stage whole A tile (64 x K bf16), fully parallel loads, one barrier ----
    const int cst = t % U4R;
    const int r0l = t / U4R;
    f32x2 cp[4], hp[4];
    if constexpr (BNA) {
        const f32x2* cpp = (const f32x2*)(bnsc + cst * 8);
        const f32x2* hpp = (const f32x2*)(bnsh + cst * 8);
#pragma unroll
        for (int j = 0; j < 4; ++j) { cp[j] = cpp[j]; hp[j] = hpp[j]; }
    }
    uint4 stg[NU];
#pragma unroll
    for (int u = 0; u < NU; ++u) {
        int rl = r0l + u * RPU;
        stg[u] = *(const uint4*)((const char*)A + (size_t)(rowBase + rl) * (K * 2) + (size_t)cst * 16);
    }
#pragma unroll
    for (int u = 0; u < NU; ++u) {
        uint4 v = stg[u];
        if constexpr (BNA) {
            v.x = bnrelu_pk(v.x, cp[0], hp[0]);
            v.y = bnrelu_pk(v.y, cp[1], hp[1]);
            v.z = bnrelu_pk(v.z, cp[2], hp[2]);
            v.w = bnrelu_pk(v.w, cp[3], hp[3]);
        }
        int rl = r0l + u * RPU;
        *(uint4*)&As[rl * LROW + cst * 8] = v;
    }
    __syncthreads();

    const __hip_bfloat16* bptr[WNB];
#pragma unroll
    for (int nf = 0; nf < WNB; ++nf)
        bptr[nf] = Wswz + (size_t)(wn / 16 + nf) * KSTEPS * 512 + (size_t)lane * 8;

    f32x4 acc[4][WNB];
    const f32x4 z = {0.f, 0.f, 0.f, 0.f};
#pragma unroll
    for (int mf = 0; mf < 4; ++mf)
#pragma unroll
        for (int nf = 0; nf < WNB; ++nf) acc[mf][nf] = z;

#pragma unroll
    for (int ks = 0; ks < KSTEPS; ++ks) {
        bf16x8 a[4], b[WNB];
#pragma unroll
        for (int nf = 0; nf < WNB; ++nf)
            b[nf] = __builtin_bit_cast(bf16x8, *(const uint4*)(bptr[nf] + ks * 512));
#pragma unroll
        for (int mf = 0; mf < 4; ++mf)
            a[mf] = __builtin_bit_cast(bf16x8, *(const uint4*)&As[(mf * 16 + cl) * LROW + ks * 32 + q * 8]);
#pragma unroll
        for (int mf = 0; mf < 4; ++mf)
#pragma unroll
            for (int nf = 0; nf < WNB; ++nf)
                acc[mf][nf] = __builtin_amdgcn_mfma_f32_16x16x32_bf16(a[mf], b[nf], acc[mf][nf], 0, 0, 0);
    }

    // ---- transpose accumulators through LDS, then coalesced uint4 stores ----
    __syncthreads();   // all waves done reading As before Ct overwrites it
#pragma unroll
    for (int mf = 0; mf < 4; ++mf)
#pragma unroll
        for (int i = 0; i < 4; ++i) {
            int row = mf * 16 + q * 4 + i;
            float dv = PRESCALE ? dinvp[rowBase + row] : 1.0f;
#pragma unroll
            for (int nf = 0; nf < WNB; ++nf)
                Ct[row * LROWC + wn + nf * 16 + cl] = f2b(PRESCALE ? acc[mf][nf][i] * dv : acc[mf][nf][i]);
        }
    __syncthreads();
    constexpr int U4C = CS / 8;              // uint4 per output row
    constexpr int NC  = 64 * U4C / 256;      // per thread
#pragma unroll
    for (int u = 0; u < NC; ++u) {
        int idx = u * 256 + t;
        int row = idx / U4C, c = idx % U4C;
        uint4 v = *(const uint4*)&Ct[row * LROWC + c * 8];
        *(uint4*)&Cout[(rowBase + row) * CS + c * 8] = v;
    }

    if constexpr (STATS) {
        float* rb = statr + (size_t)(blockIdx.x & (NREP - 1)) * 512;
#pragma unroll
        for (int nf = 0; nf < WNB; ++nf) {
            float s = 0.f, s2 = 0.f;
#pragma unroll
            for (int mf = 0; mf < 4; ++mf)
#pragma unroll
                for (int i = 0; i < 4; ++i) {
                    float v = acc[mf][nf][i];
                    s += v; s2 += v * v;
                }
            s  += __shfl_xor(s, 16);  s  += __shfl_xor(s, 32);
            s2 += __shfl_xor(s2, 16); s2 += __shfl_xor(s2, 32);
            if (q == 0) {
                int col = wn + nf * 16 + cl;
                if (col < NOUT) {
                    atomicAdd(&rb[col], s);
                    atomicAdd(&rb[256 + col], s2);
                }
            }
        }
        __syncthreads();                       // drains this block's atomics before done
        __shared__ int lastf;
        if (threadIdx.x == 0) lastf = (atomicAdd(done, 1) == (int)gridDim.x - 1) ? 1 : 0;
        __syncthreads();
        if (lastf) {
            const int tt = threadIdx.x;        // 256 threads
            float su = 0.f, qu = 0.f;
#pragma unroll
            for (int r = 0; r < NREP; ++r) {
                su += atomicAdd(&statr[(size_t)r * 512 + tt], 0.0f);       // L2-coherent reads
                qu += atomicAdd(&statr[(size_t)r * 512 + 256 + tt], 0.0f);
            }
            float mu = su * (1.0f / NNODES);
            float var = qu * (1.0f / NNODES) - mu * mu;
            if (var < 0.f) var = 0.f;
            float sc = gamma[tt] * rsqrtf(var + EPS);
            scale[tt] = sc;
            shift[tt] = beta[tt] - mu * sc;
        }
    }
}

// ---------------- BN stats over bf16 matrix, vectorized, replicated accumulators ----------------
__global__ __launch_bounds__(256) void k_stats(const uint4* __restrict__ Zu,
                                               float* __restrict__ statr,
                                               const float* __restrict__ gamma,
                                               const float* __restrict__ beta,
                                               float* __restrict__ scale, float* __restrict__ shift,
                                               int* __restrict__ done) {
    __shared__ float reds[8][256];
    __shared__ float redq[8][256];
    const int t = threadIdx.x;
    const int cg = t & 31;        // col group: cols cg*8 .. cg*8+7
    const int rs = t >> 5;        // row slice: rows rs*32 .. rs*32+31 of this block's 256
    const long r0 = (long)blockIdx.x * 256 + (long)rs * 32;
    float s[8], q[8];
#pragma unroll
    for (int j = 0; j < 8; ++j) { s[j] = 0.f; q[j] = 0.f; }
    for (int i = 0; i < 32; ++i) {
        long r = r0 + i;
        if (r >= NNODES) break;
        uint4 u = Zu[r * 32 + cg];
        float v0 = bflo(u.x), v1 = bfhi(u.x), v2 = bflo(u.y), v3 = bfhi(u.y);
        float v4 = bflo(u.z), v5 = bfhi(u.z), v6 = bflo(u.w), v7 = bfhi(u.w);
        s[0] += v0; q[0] += v0 * v0;  s[1] += v1; q[1] += v1 * v1;
        s[2] += v2; q[2] += v2 * v2;  s[3] += v3; q[3] += v3 * v3;
        s[4] += v4; q[4] += v4 * v4;  s[5] += v5; q[5] += v5 * v5;
        s[6] += v6; q[6] += v6 * v6;  s[7] += v7; q[7] += v7 * v7;
    }
#pragma unroll
    for (int j = 0; j < 8; ++j) {
        reds[rs][cg * 8 + j] = s[j];
        redq[rs][cg * 8 + j] = q[j];
    }
    __syncthreads();
    float S = 0.f, Q = 0.f;
#pragma unroll
    for (int j = 0; j < 8; ++j) { S += reds[j][t]; Q += redq[j][t]; }
    float* rb = statr + (size_t)(blockIdx.x & (NREP - 1)) * 512;
    atomicAdd(&rb[t], S);
    atomicAdd(&rb[256 + t], Q);
    __syncthreads();                       // drains this block's atomics before done
    __shared__ int lastf;
    if (t == 0) lastf = (atomicAdd(done, 1) == (int)gridDim.x - 1) ? 1 : 0;
    __syncthreads();
    if (lastf) {
        float su = 0.f, qu = 0.f;
#pragma unroll
        for (int r = 0; r < NREP; ++r) {
            su += atomicAdd(&statr[(size_t)r * 512 + t], 0.0f);
            qu += atomicAdd(&statr[(size_t)r * 512 + 256 + t], 0.0f);
        }
        float mu = su * (1.0f / NNODES);
        float var = qu * (1.0f / NNODES) - mu * mu;
        if (var < 0.f) var = 0.f;
        float sc = gamma[t] * rsqrtf(var + EPS);
        scale[t] = sc;
        shift[t] = beta[t] - mu * sc;
    }
}

// ---------------- driver ----------------
extern "C" void kernel_launch(void* const* d_in, const int* in_sizes, int n_in,
                              void* d_out, int out_size, void* d_ws, size_t ws_size,
                              hipStream_t stream) {
    const float* x   = (const float*)d_in[0];
    const int*   ei  = (const int*)d_in[1];
    const float* W1  = (const float*)d_in[2];
    const float* g1  = (const float*)d_in[4];
    const float* be1 = (const float*)d_in[5];
    const float* W2  = (const float*)d_in[6];
    const float* g2  = (const float*)d_in[8];
    const float* be2 = (const float*)d_in[9];
    const float* W3  = (const float*)d_in[10];
    const float* b3  = (const float*)d_in[11];
    // b1 (d_in[3]) and b2 (d_in[7]) cancel exactly under BatchNorm — skipped.

    char* w = (char*)d_ws;
    size_t o = 0;
    auto alloc = [&](size_t b) { size_t r = o; o += (b + 255) & ~(size_t)255; return r; };
    int*   offs = (int*)(w + alloc((size_t)(NNODES + 1) * 4));
    float* dinv = (float*)(w + alloc((size_t)NNODES * 4));
    int*   cnt  = (int*)(w + alloc((size_t)NEB * NBUCK * 4));   // 1.6 MB
    int*   btot = (int*)(w + alloc(NBUCK * 4));
    int*   bbase= (int*)(w + alloc((NBUCK + 1) * 4));
    unsigned* ebuf = (unsigned*)(w + alloc((size_t)NEDGES * 4));
    int*   csr  = (int*)(w + alloc((size_t)NEDGES * 4));
    float* stats = (float*)(w + alloc((2 * NREP * 512 + 8) * 4)); // statr1[NREP][512], statr2[NREP][512], done1, done2
    float* bnp   = (float*)(w + alloc(4 * 256 * 4));            // scale1,shift1,scale2,shift2
    unsigned short* w1s = (unsigned short*)(w + alloc(65536));
    unsigned short* w2s = (unsigned short*)(w + alloc(131072));
    unsigned short* w3s = (unsigned short*)(w + alloc(32768));  // 4 col-groups (4th zeroed)
    __hip_bfloat16* xb   = (__hip_bfloat16*)(w + alloc((size_t)NNODES * 128 * 2));
    __hip_bfloat16* buf0 = (__hip_bfloat16*)(w + alloc((size_t)NNODES * 128 * 2)); // y0 -> T3' (stride 64)
    __hip_bfloat16* buf1 = (__hip_bfloat16*)(w + alloc((size_t)NNODES * 256 * 2)); // Z1 -> Z2
    __hip_bfloat16* buf2 = (__hip_bfloat16*)(w + alloc((size_t)NNODES * 256 * 2)); // y2'

    float* statr1 = stats;                      // NREP x 512
    float* statr2 = stats + NREP * 512;         // NREP x 512
    int*   done1 = (int*)(stats + 2 * NREP * 512);
    int*   done2 = done1 + 1;
    float* scale1 = bnp;        float* shift1 = bnp + 256;
    float* scale2 = bnp + 512;  float* shift2 = bnp + 768;

    const int SB = (NNODES + 255) / 256;  // 782
    const int GB = NNODES / 64;           // 3125 gemm blocks (200000 % 64 == 0)

    // CSR build + fused weight swizzle + replicated-stats zeroing (no memset dispatch)
    k_cnt<<<NEB + 64, 256, 0, stream>>>(ei, cnt, W1, W2, W3, w1s, w2s, w3s, (unsigned*)stats);
    k_bscan<<<(NBUCK * 64 + 255) / 256, 256, 0, stream>>>(cnt, btot);
    k_place<<<NEB, 256, 0, stream>>>(ei, ei + NEDGES, cnt, btot, bbase, ebuf);
    k_sort2<<<NBUCK, 256, 0, stream>>>(ebuf, bbase, offs, dinv, csr, x, (uint4*)xb);

    // layer 1: BN1 stats fused into GEMM epilogue (replicated), finalized by last block;
    // aggf split into 2 node-range chunks (diagnostic: keeps top-5 informative)
    for (int c = 0; c < 2; ++c)
        k_aggf<<<AGGF_CHUNK / 4, 256, 0, stream>>>((const uint4*)xb, offs, csr, dinv, (uint4*)buf0, c * AGGF_CHUNK);
    k_gemm<128, 4, 256, false, false, true><<<GB, 256, 0, stream>>>(buf0, (const __hip_bfloat16*)w1s, nullptr, nullptr, nullptr, (unsigned short*)buf1, NNODES, 256, statr1, g1, be1, scale1, shift1, done1);

    // layer 2: gemm2 applies BN1+ReLU once at LDS staging, prescales C by dinv;
    // aggb split into 4 node-range chunks (diagnostic)
    k_gemm<256, 4, 256, true, true, false><<<GB, 256, 0, stream>>>(buf1, (const __hip_bfloat16*)w2s, dinv, scale1, shift1, (unsigned short*)buf2, NNODES, 256, nullptr, nullptr, nullptr, nullptr, nullptr, nullptr);
    for (int c = 0; c < 4; ++c)
        k_aggb<<<AGGB_CHUNK / 4, 256, 0, stream>>>((const uint4*)buf2, offs, csr, dinv, (uint4*)buf1, c * AGGB_CHUNK);
    k_stats<<<SB, 256, 0, stream>>>((const uint4*)buf1, statr2, g2, be2, scale2, shift2, done2);

    // layer 3: gemm3 applies BN2+ReLU once at LDS staging, prescales C by dinv, writes 128B-padded rows;
    // then fused agg+softmax reads exactly one cache line per gathered row
    k_gemm<256, 1, 64, true, true, false><<<GB, 256, 0, stream>>>(buf1, (const __hip_bfloat16*)w3s, dinv, scale2, shift2, (unsigned short*)buf0, NNODES, 40, nullptr, nullptr, nullptr, nullptr, nullptr, nullptr);
    k_agg3<<<NNODES / 4, 256, 0, stream>>>((const uint4*)buf0, offs, csr, dinv, b3, (float*)d_out);
}

// Round 12
// 906.903 us; speedup vs baseline: 1.1485x; 1.0337x over previous
//
#include <hip/hip_runtime.h>
#include <hip/hip_bf16.h>

#define NNODES 200000
#define NEDGES 3200000
#define NBUCK 782            // ceil(NNODES/256)
#define NEB 512              // edge blocks for counting sort
#define EPB (NEDGES / NEB)   // 6250 edges per block
#define EPS 1e-5f
#define AGGB_CHUNK 50000     // nodes per aggb chunk (4 chunks) — diagnostic split
#define AGGF_CHUNK 100000    // nodes per aggf chunk (2 chunks) — diagnostic split
#define NREP 16              // stats accumulator replicas (kills hot-address atomic queueing)

typedef __bf16 bf16x8 __attribute__((ext_vector_type(8)));
typedef float  f32x4  __attribute__((ext_vector_type(4)));
typedef float  f32x2  __attribute__((ext_vector_type(2)));

__device__ __forceinline__ float bflo(unsigned u) { return __uint_as_float(u << 16); }
__device__ __forceinline__ float bfhi(unsigned u) { return __uint_as_float(u & 0xffff0000u); }
__device__ __forceinline__ unsigned short f2b(float f) {
    return __builtin_bit_cast(unsigned short, __float2bfloat16(f));
}
__device__ __forceinline__ unsigned pk2(float a, float b) {
    return (unsigned)f2b(a) | ((unsigned)f2b(b) << 16);
}
// BN+ReLU on a packed bf16 pair, using packed f32 math (v_pk_fma_f32 / v_pk_max_f32)
__device__ __forceinline__ unsigned bnrelu_pk(unsigned u, f32x2 c, f32x2 h) {
    f32x2 v = { __uint_as_float(u << 16), __uint_as_float(u & 0xffff0000u) };
    v = __builtin_elementwise_fma(v, c, h);
    const f32x2 z = {0.f, 0.f};
    v = __builtin_elementwise_max(v, z);
    return pk2(v[0], v[1]);
}

// ---------------- weight swizzle helper ----------------
__device__ __forceinline__ void prepw_one(const float* __restrict__ W,
                                          unsigned short* __restrict__ Wswz,
                                          int K, int NOUT, int t) {
    int KSTEPS = K / 32;
    int lane = t & 63;
    int ks = (t >> 6) % KSTEPS;
    int g  = (t >> 6) / KSTEPS;
    int c = lane & 15, q = lane >> 4;
    int col = g * 16 + c;
    int k0 = ks * 32 + q * 8;
    unsigned short vals[8];
#pragma unroll
    for (int j = 0; j < 8; ++j)
        vals[j] = (col < NOUT) ? f2b(W[(size_t)(k0 + j) * NOUT + col]) : (unsigned short)0;
    *(uint4*)((char*)Wswz + (size_t)t * 16) = __builtin_bit_cast(uint4, vals);
}

// ---------------- CSR build step 1: per-block bucket histogram
// ----------------  + fused weight swizzle + stats zeroing (independent blocks) ----------------
__global__ __launch_bounds__(256) void k_cnt(const int* __restrict__ row, int* __restrict__ cnt,
                                             const float* __restrict__ W1,
                                             const float* __restrict__ W2,
                                             const float* __restrict__ W3,
                                             unsigned short* __restrict__ w1s,
                                             unsigned short* __restrict__ w2s,
                                             unsigned short* __restrict__ w3s,
                                             unsigned* __restrict__ statsz) {
    const int blk = blockIdx.x;
    if (blk >= NEB + 56) {                       // zero replicated stats + done counters
        const int zid = blk - (NEB + 56);        // 8 zero blocks
        for (int i = zid * 256 + threadIdx.x; i < 2 * NREP * 512 + 2; i += 8 * 256)
            statsz[i] = 0u;
        return;
    }
    if (blk >= NEB) {                            // weight swizzle: 56 blocks = 14336 threads
        int t = (blk - NEB) * 256 + threadIdx.x;
        if (t < 4096) prepw_one(W1, w1s, 128, 256, t);
        else if (t < 12288) prepw_one(W2, w2s, 256, 256, t - 4096);
        else if (t < 14336) prepw_one(W3, w3s, 256, 40, t - 12288);   // 4 col-groups, zero-padded
        return;
    }
    __shared__ int h[NBUCK];
    for (int i = threadIdx.x; i < NBUCK; i += 256) h[i] = 0;
    __syncthreads();
    const int e0 = blk * EPB;
    for (int i = e0 + threadIdx.x; i < e0 + EPB; i += 256)
        atomicAdd(&h[row[i] >> 8], 1);
    __syncthreads();
    for (int i = threadIdx.x; i < NBUCK; i += 256)
        cnt[(size_t)blk * NBUCK + i] = h[i];
}

__global__ __launch_bounds__(256) void k_bscan(int* __restrict__ cnt, int* __restrict__ btot) {
    const int wv = (blockIdx.x * 256 + threadIdx.x) >> 6;   // bucket
    const int lane = threadIdx.x & 63;
    if (wv >= NBUCK) return;
    int v[8]; int s = 0;
#pragma unroll
    for (int j = 0; j < 8; ++j) {
        v[j] = cnt[(size_t)(lane * 8 + j) * NBUCK + wv];
        s += v[j];
    }
    int excl = s;
#pragma unroll
    for (int o = 1; o < 64; o <<= 1) {
        int t = __shfl_up(excl, o);
        if (lane >= o) excl += t;
    }
    excl -= s;
    if (lane == 63) btot[wv] = excl + s;
    int base = excl;
#pragma unroll
    for (int j = 0; j < 8; ++j) {
        int t = v[j];
        cnt[(size_t)(lane * 8 + j) * NBUCK + wv] = base;
        base += t;
    }
}

// ---------------- place: in-block scan of btot (replaces k_btscan) + scatter ----------------
__global__ __launch_bounds__(256) void k_place(const int* __restrict__ row, const int* __restrict__ col,
                                               const int* __restrict__ cnt, const int* __restrict__ btot,
                                               int* __restrict__ bbase, unsigned* __restrict__ ebuf) {
    __shared__ int sbb[NBUCK];
    __shared__ int tp[256];
    __shared__ int base[NBUCK];
    const int t = threadIdx.x;
    // chunked exclusive scan of btot[0..NBUCK): thread t owns [t*4, t*4+4)
    int v[4]; int loc = 0;
    const int i0 = t * 4;
#pragma unroll
    for (int j = 0; j < 4; ++j) {
        int idx = i0 + j;
        v[j] = (idx < NBUCK) ? btot[idx] : 0;
        loc += v[j];
    }
    tp[t] = loc;
    __syncthreads();
    for (int off = 1; off < 256; off <<= 1) {
        int u = (t >= off) ? tp[t - off] : 0;
        __syncthreads();
        tp[t] += u;
        __syncthreads();
    }
    int run = tp[t] - loc;   // exclusive prefix of this thread's chunk
#pragma unroll
    for (int j = 0; j < 4; ++j) {
        int idx = i0 + j;
        if (idx < NBUCK) sbb[idx] = run;
        run += v[j];
    }
    __syncthreads();
    if (blockIdx.x == 0) {   // publish for k_sort2
        for (int i = t; i < NBUCK; i += 256) bbase[i] = sbb[i];
        if (t == 0) bbase[NBUCK] = NEDGES;
    }
    for (int i = t; i < NBUCK; i += 256)
        base[i] = sbb[i] + cnt[(size_t)blockIdx.x * NBUCK + i];
    __syncthreads();
    const int e0 = blockIdx.x * EPB;
    for (int i = e0 + t; i < e0 + EPB; i += 256) {
        int r = row[i], c = col[i];
        int p = atomicAdd(&base[r >> 8], 1);
        ebuf[p] = ((unsigned)(r & 255) << 18) | (unsigned)c;   // col < 2^18
    }
}

// fused: per-bucket degree count -> offs/dinv -> rank -> final CSR -> x cast (uses fresh dinv)
__global__ __launch_bounds__(256) void k_sort2(const unsigned* __restrict__ ebuf,
                                               const int* __restrict__ bbase,
                                               int* __restrict__ offs, float* __restrict__ dinv,
                                               int* __restrict__ csr,
                                               const float* __restrict__ x,
                                               uint4* __restrict__ xb) {
    __shared__ int cnt[256];
    __shared__ int sofs[256];
    __shared__ int sc[256];
    __shared__ float sdinv[256];
    const int b = blockIdx.x;
    const int t = threadIdx.x;
    const int n0 = b * 256;
    cnt[t] = 0;
    __syncthreads();
    const int s = bbase[b], e = bbase[b + 1];
    for (int i = s + t; i < e; i += 256)
        atomicAdd(&cnt[ebuf[i] >> 18], 1);
    __syncthreads();
    const int c = cnt[t];
    sc[t] = c;
    __syncthreads();
    for (int off = 1; off < 256; off <<= 1) {
        int v = (t >= off) ? sc[t - off] : 0;
        __syncthreads();
        sc[t] += v;
        __syncthreads();
    }
    const int excl = sc[t] - c;
    sofs[t] = s + excl;
    const int n = n0 + t;
    float dv = rsqrtf((float)(c + 1));
    sdinv[t] = dv;
    if (n < NNODES) {
        offs[n] = s + excl;
        dinv[n] = dv;
    }
    if (b == NBUCK - 1 && t == 0) offs[NNODES] = NEDGES;
    cnt[t] = 0;
    __syncthreads();
    for (int i = s + t; i < e; i += 256) {
        unsigned v = ebuf[i];
        int nl = v >> 18;
        int rank = atomicAdd(&cnt[nl], 1);
        csr[sofs[nl] + rank] = (int)(v & 0x3FFFFu);
    }
    // fused x -> prescaled bf16 cast for this block's nodes (coalesced 128 KB read)
    const int nn = (NNODES - n0 < 256) ? (NNODES - n0) : 256;
    const float4* xp = (const float4*)(x + (size_t)n0 * 128);
    uint4* xo = xb + (size_t)n0 * 16;
    const int lim = nn * 16;
    for (int i = t; i < lim; i += 256) {
        float d = sdinv[i >> 4];
        float4 a = xp[i * 2], bb = xp[i * 2 + 1];
        uint4 o;
        o.x = pk2(a.x * d, a.y * d);  o.y = pk2(a.z * d, a.w * d);
        o.z = pk2(bb.x * d, bb.y * d); o.w = pk2(bb.z * d, bb.w * d);
        xo[i] = o;
    }
}

// ---------------- aggregation: F=128 rows (16 x uint4), up to 16 edges in flight,
// ---------------- node-range chunked (diagnostic split; nodes independent) ----------------
__global__ __launch_bounds__(256) void k_aggf(const uint4* __restrict__ in,
                                              const int* __restrict__ offs,
                                              const int* __restrict__ csr,
                                              const float* __restrict__ dinv,
                                              uint4* __restrict__ out,
                                              int nbase) {
    const int lane = threadIdx.x & 63;
    const int grp = lane >> 4;
    const int fl = lane & 15;
    const int node = nbase + blockIdx.x * 4 + (threadIdx.x >> 6);
    const int p0 = offs[node];
    const int K = offs[node + 1] - p0 + 1;   // +1 virtual self item at k=0
    float a0=0,a1=0,a2=0,a3=0,a4=0,a5=0,a6=0,a7=0;
    auto accum = [&](uint4 u) {
        a0 += bflo(u.x); a1 += bfhi(u.x);
        a2 += bflo(u.y); a3 += bfhi(u.y);
        a4 += bflo(u.z); a5 += bfhi(u.z);
        a6 += bflo(u.w); a7 += bfhi(u.w);
    };
    int k = 0;
    for (; k + 16 <= K; k += 16) {
        int j0 = k + grp;
        int i0 = (j0 == 0) ? node : csr[p0 + j0 - 1];
        int i1 = csr[p0 + k + 3 + grp];
        int i2 = csr[p0 + k + 7 + grp];
        int i3 = csr[p0 + k + 11 + grp];
        uint4 u0 = in[(size_t)i0 * 16 + fl];
        uint4 u1 = in[(size_t)i1 * 16 + fl];
        uint4 u2 = in[(size_t)i2 * 16 + fl];
        uint4 u3 = in[(size_t)i3 * 16 + fl];
        accum(u0); accum(u1); accum(u2); accum(u3);
    }
    for (; k + 8 <= K; k += 8) {
        int j0 = k + grp;
        int i0 = (j0 == 0) ? node : csr[p0 + j0 - 1];
        int i1 = csr[p0 + k + 3 + grp];
        uint4 u0 = in[(size_t)i0 * 16 + fl];
        uint4 u1 = in[(size_t)i1 * 16 + fl];
        accum(u0); accum(u1);
    }
    for (; k + 4 <= K; k += 4) {
        int j0 = k + grp;
        int i0 = (j0 == 0) ? node : csr[p0 + j0 - 1];
        accum(in[(size_t)i0 * 16 + fl]);
    }
    int rem = K - k;
    if (grp < rem) {
        int j0 = k + grp;
        int i0 = (j0 == 0) ? node : csr[p0 + j0 - 1];
        accum(in[(size_t)i0 * 16 + fl]);
    }
#define RED(v) v += __shfl_xor(v, 32); v += __shfl_xor(v, 16);
    RED(a0) RED(a1) RED(a2) RED(a3) RED(a4) RED(a5) RED(a6) RED(a7)
#undef RED
    if (grp == 0) {
        const float d = dinv[node];
        uint4 o;
        o.x = pk2(a0 * d, a1 * d); o.y = pk2(a2 * d, a3 * d);
        o.z = pk2(a4 * d, a5 * d); o.w = pk2(a6 * d, a7 * d);
        out[(size_t)node * 16 + fl] = o;
    }
}

// ---------------- aggregation: F=256 rows (32 x uint4), 2 edges per load, unroll 4,
// ---------------- node-range chunked (diagnostic split; nodes independent) ----------------
__global__ __launch_bounds__(256) void k_aggb(const uint4* __restrict__ in,
                                              const int* __restrict__ offs,
                                              const int* __restrict__ csr,
                                              const float* __restrict__ dinv,
                                              uint4* __restrict__ out,
                                              int nbase) {
    const int lane = threadIdx.x & 63;
    const int half = lane >> 5;
    const int fl = lane & 31;
    const int node = nbase + blockIdx.x * 4 + (threadIdx.x >> 6);
    const int p0 = offs[node];
    const int K = offs[node + 1] - p0 + 1;
    float a0=0,a1=0,a2=0,a3=0,a4=0,a5=0,a6=0,a7=0;
    auto accum = [&](uint4 u) {
        a0 += bflo(u.x); a1 += bfhi(u.x);
        a2 += bflo(u.y); a3 += bfhi(u.y);
        a4 += bflo(u.z); a5 += bfhi(u.z);
        a6 += bflo(u.w); a7 += bfhi(u.w);
    };
    auto idxAt = [&](int j) -> int { return (j == 0) ? node : csr[p0 + j - 1]; };
    int k = 0;
    for (; k + 8 <= K; k += 8) {
        int i0 = idxAt(k + half);
        int i1 = csr[p0 + k + 1 + half];
        int i2 = csr[p0 + k + 3 + half];
        int i3 = csr[p0 + k + 5 + half];
        uint4 u0 = in[(size_t)i0 * 32 + fl];
        uint4 u1 = in[(size_t)i1 * 32 + fl];
        uint4 u2 = in[(size_t)i2 * 32 + fl];
        uint4 u3 = in[(size_t)i3 * 32 + fl];
        accum(u0); accum(u1); accum(u2); accum(u3);
    }
    for (; k + 2 <= K; k += 2) {
        accum(in[(size_t)idxAt(k + half) * 32 + fl]);
    }
    if (k < K && half == 0) {
        accum(in[(size_t)idxAt(k) * 32 + fl]);
    }
#define RED(v) v += __shfl_xor(v, 32);
    RED(a0) RED(a1) RED(a2) RED(a3) RED(a4) RED(a5) RED(a6) RED(a7)
#undef RED
    if (half == 0) {
        const float d = dinv[node];
        uint4 o;
        o.x = pk2(a0 * d, a1 * d); o.y = pk2(a2 * d, a3 * d);
        o.z = pk2(a4 * d, a5 * d); o.w = pk2(a6 * d, a7 * d);
        out[(size_t)node * 32 + fl] = o;
    }
}

// ---------------- final layer: 4 nodes per WAVE (16 lanes each: 3 edge-slots x 5 feat-slots),
// ---------------- amortizes the reduction+softmax tail 4x; rows padded to 128 B ----------------
__global__ __launch_bounds__(256) void k_agg3(const uint4* __restrict__ T3b,
                                              const int* __restrict__ offs,
                                              const int* __restrict__ csr,
                                              const float* __restrict__ dinv,
                                              const float* __restrict__ b3,
                                              float* __restrict__ out) {
    const int lane = threadIdx.x & 63;
    const int il   = lane & 15;          // index within 16-lane node group
    const int grp  = il / 5;             // edge slot 0..2; il==15 -> grp 3 (idle)
    const int fl   = il - grp * 5;       // feature 16B-slot 0..4
    const bool act = grp < 3;
    const int node = blockIdx.x * 16 + (threadIdx.x >> 4);
    const int p0 = offs[node];
    const int K = offs[node + 1] - p0 + 1;   // +1 virtual self item at j=0
    float a0=0,a1=0,a2=0,a3=0,a4=0,a5=0,a6=0,a7=0;
    auto accum = [&](uint4 u) {
        a0 += bflo(u.x); a1 += bfhi(u.x);
        a2 += bflo(u.y); a3 += bfhi(u.y);
        a4 += bflo(u.z); a5 += bfhi(u.z);
        a6 += bflo(u.w); a7 += bfhi(u.w);
    };
    const char* Tb = (const char*)T3b;
    if (act) {
        int k = 0;
        for (; k + 3 <= K; k += 3) {
            int j = k + grp;
            int i0 = (j == 0) ? node : csr[p0 + j - 1];
            accum(*(const uint4*)(Tb + (size_t)i0 * 128 + fl * 16));
        }
        int rem = K - k;
        if (grp < rem) {
            int j = k + grp;
            int i0 = (j == 0) ? node : csr[p0 + j - 1];
            accum(*(const uint4*)(Tb + (size_t)i0 * 128 + fl * 16));
        }
    }
    // reduce across the 3 edge-slots: lanes il<5 pull from il+5 and il+10 (same group)
#define RED3(v) { float t1 = __shfl(v, lane + 5); float t2 = __shfl(v, lane + 10); v += t1 + t2; }
    RED3(a0) RED3(a1) RED3(a2) RED3(a3) RED3(a4) RED3(a5) RED3(a6) RED3(a7)
#undef RED3
    const float d = dinv[node];
    float v[8];
    if (il < 5) {
        const float4* bp = (const float4*)(b3 + il * 8);
        float4 b01 = bp[0], b23 = bp[1];
        v[0] = a0 * d + b01.x; v[1] = a1 * d + b01.y;
        v[2] = a2 * d + b01.z; v[3] = a3 * d + b01.w;
        v[4] = a4 * d + b23.x; v[5] = a5 * d + b23.y;
        v[6] = a6 * d + b23.z; v[7] = a7 * d + b23.w;
    } else {
#pragma unroll
        for (int j = 0; j < 8; ++j) v[j] = -INFINITY;
    }
    float m = v[0];
#pragma unroll
    for (int j = 1; j < 8; ++j) m = fmaxf(m, v[j]);
    const int gbase = lane & ~15;        // first lane of this node group within the wave
    float mm = __shfl(m, gbase);
#pragma unroll
    for (int l = 1; l < 5; ++l) mm = fmaxf(mm, __shfl(m, gbase + l));
    float e = 0.f;
    if (il < 5) {
#pragma unroll
        for (int j = 0; j < 8; ++j) e += __expf(v[j] - mm);
    }
    float s = __shfl(e, gbase);
#pragma unroll
    for (int l = 1; l < 5; ++l) s += __shfl(e, gbase + l);
    float ls = __logf(s);
    if (il < 5) {
        float* op = out + (size_t)node * 40 + il * 8;
        float4 o0 = {v[0] - mm - ls, v[1] - mm - ls, v[2] - mm - ls, v[3] - mm - ls};
        float4 o1 = {v[4] - mm - ls, v[5] - mm - ls, v[6] - mm - ls, v[7] - mm - ls};
        *(float4*)op = o0;
        *(float4*)(op + 4) = o1;
    }
}

// ---------------- MFMA GEMM: whole 64-row A tile staged to LDS once, BN+ReLU at staging,
// ---------------- LDS-transposed COALESCED uint4 C-store, dinv prescale,
// ---------------- replicated fused stats + BN finalize (done-counter) ----------------
template <int K, int WNB, int CS, bool PRESCALE, bool BNA, bool STATS>
__global__ __launch_bounds__(256) void k_gemm(const __hip_bfloat16* __restrict__ A,
                                              const __hip_bfloat16* __restrict__ Wswz,
                                              const float* __restrict__ dinvp,
                                              const float* __restrict__ bnsc,
                                              const float* __restrict__ bnsh,
                                              unsigned short* __restrict__ Cout,
                                              int M, int NOUT,
                                              float* __restrict__ statr,
                                              const float* __restrict__ gamma,
                                              const float* __restrict__ beta,
                                              float* __restrict__ scale,
                                              float* __restrict__ shift,
                                              int* __restrict__ done) {
    constexpr int KSTEPS = K / 32;
    constexpr int LROW   = K + 8;            // bf16 per A-LDS row (+16B pad)
    constexpr int U4R    = K / 8;            // uint4 per A row
    constexpr int NU     = K / 32;           // uint4 staged per thread
    constexpr int RPU    = 256 / U4R;        // rows advanced per staging step
    constexpr int LROWC  = CS + 16;          // bf16 per C-LDS row: +32B pad -> row stride ≡8 dwords mod 32
    constexpr int ABYTES = 64 * LROW * 2;
    constexpr int CBYTES = 64 * LROWC * 2;
    constexpr int SBYTES = (ABYTES > CBYTES) ? ABYTES : CBYTES;
    __shared__ __align__(16) char smem[SBYTES];
    unsigned short* As = (unsigned short*)smem;
    unsigned short* Ct = (unsigned short*)smem;   // union: Ct used after compute

    const int t = threadIdx.x;
    const int lane = t & 63;
    const int wid  = t >> 6;
    const int wn = wid * (WNB * 16);
    const long rowBase = (long)blockIdx.x * 64;
    const int cl = lane & 15, q = lane >> 4;

    // ---- stage whole A tile (64 x K bf16), fully parallel loads, one barrier ----
    const int cst = t % U4R;
    const int r0l = t / U4R;
    f32x2 cp[4], hp[4];
    if constexpr (BNA) {
        const f32x2* cpp = (const f32x2*)(bnsc + cst * 8);
        const f32x2* hpp = (const f32x2*)(bnsh + cst * 8);
#pragma unroll
        for (int j = 0; j < 4; ++j) { cp[j] = cpp[j]; hp[j] = hpp[j]; }
    }
    uint4 stg[NU];
#pragma unroll
    for (int u = 0; u < NU; ++u) {
        int rl = r0l + u * RPU;
        stg[u] = *(const uint4*)((const char*)A + (size_t)(rowBase + rl) * (K * 2) + (size_t)cst * 16);
    }
#pragma unroll
    for (int u = 0; u < NU; ++u) {
        uint4 v = stg[u];
        if constexpr (BNA) {
            v.x = bnrelu_pk(v.x, cp[0], hp[0]);
            v.y = bnrelu_pk(v.y, cp[1], hp[1]);
            v.z = bnrelu_pk(v.z, cp[2], hp[2]);
            v.w = bnrelu_pk(v.w, cp[3], hp[3]);
        }
        int rl = r0l + u * RPU;
        *(uint4*)&As[rl * LROW + cst * 8] = v;
    }
    __syncthreads();

    const __hip_bfloat16* bptr[WNB];
#pragma unroll
    for (int nf = 0; nf < WNB; ++nf)
        bptr[nf] = Wswz + (size_t)(wn / 16 + nf) * KSTEPS * 512 + (size_t)lane * 8;

    f32x4 acc[4][WNB];
    const f32x4 z = {0.f, 0.f, 0.f, 0.f};
#pragma unroll
    for (int mf = 0; mf < 4; ++mf)
#pragma unroll
        for (int nf = 0; nf < WNB; ++nf) acc[mf][nf] = z;

#pragma unroll
    for (int ks = 0; ks < KSTEPS; ++ks) {
        bf16x8 a[4], b[WNB];
#pragma unroll
        for (int nf = 0; nf < WNB; ++nf)
            b[nf] = __builtin_bit_cast(bf16x8, *(const uint4*)(bptr[nf] + ks * 512));
#pragma unroll
        for (int mf = 0; mf < 4; ++mf)
            a[mf] = __builtin_bit_cast(bf16x8, *(const uint4*)&As[(mf * 16 + cl) * LROW + ks * 32 + q * 8]);
#pragma unroll
        for (int mf = 0; mf < 4; ++mf)
#pragma unroll
            for (int nf = 0; nf < WNB; ++nf)
                acc[mf][nf] = __builtin_amdgcn_mfma_f32_16x16x32_bf16(a[mf], b[nf], acc[mf][nf], 0, 0, 0);
    }

    // ---- transpose accumulators through LDS, then coalesced uint4 stores ----
    __syncthreads();   // all waves done reading As before Ct overwrites it
#pragma unroll
    for (int mf = 0; mf < 4; ++mf)
#pragma unroll
        for (int i = 0; i < 4; ++i) {
            int row = mf * 16 + q * 4 + i;
            float dv = PRESCALE ? dinvp[rowBase + row] : 1.0f;
#pragma unroll
            for (int nf = 0; nf < WNB; ++nf)
                Ct[row * LROWC + wn + nf * 16 + cl] = f2b(PRESCALE ? acc[mf][nf][i] * dv : acc[mf][nf][i]);
        }
    __syncthreads();
    constexpr int U4C = CS / 8;              // uint4 per output row
    constexpr int NC  = 64 * U4C / 256;      // per thread
#pragma unroll
    for (int u = 0; u < NC; ++u) {
        int idx = u * 256 + t;
        int row = idx / U4C, c = idx % U4C;
        uint4 v = *(const uint4*)&Ct[row * LROWC + c * 8];
        *(uint4*)&Cout[(rowBase + row) * CS + c * 8] = v;
    }

    if constexpr (STATS) {
        float* rb = statr + (size_t)(blockIdx.x & (NREP - 1)) * 512;
#pragma unroll
        for (int nf = 0; nf < WNB; ++nf) {
            float s = 0.f, s2 = 0.f;
#pragma unroll
            for (int mf = 0; mf < 4; ++mf)
#pragma unroll
                for (int i = 0; i < 4; ++i) {
                    float v = acc[mf][nf][i];
                    s += v; s2 += v * v;
                }
            s  += __shfl_xor(s, 16);  s  += __shfl_xor(s, 32);
            s2 += __shfl_xor(s2, 16); s2 += __shfl_xor(s2, 32);
            if (q == 0) {
                int col = wn + nf * 16 + cl;
                if (col < NOUT) {
                    atomicAdd(&rb[col], s);
                    atomicAdd(&rb[256 + col], s2);
                }
            }
        }
        __syncthreads();                       // drains this block's atomics before done
        __shared__ int lastf;
        if (threadIdx.x == 0) lastf = (atomicAdd(done, 1) == (int)gridDim.x - 1) ? 1 : 0;
        __syncthreads();
        if (lastf) {
            const int tt = threadIdx.x;        // 256 threads
            float su = 0.f, qu = 0.f;
#pragma unroll
            for (int r = 0; r < NREP; ++r) {
                su += atomicAdd(&statr[(size_t)r * 512 + tt], 0.0f);       // L2-coherent reads
                qu += atomicAdd(&statr[(size_t)r * 512 + 256 + tt], 0.0f);
            }
            float mu = su * (1.0f / NNODES);
            float var = qu * (1.0f / NNODES) - mu * mu;
            if (var < 0.f) var = 0.f;
            float sc = gamma[tt] * rsqrtf(var + EPS);
            scale[tt] = sc;
            shift[tt] = beta[tt] - mu * sc;
        }
    }
}

// ---------------- BN stats over bf16 matrix, vectorized, replicated accumulators ----------------
__global__ __launch_bounds__(256) void k_stats(const uint4* __restrict__ Zu,
                                               float* __restrict__ statr,
                                               const float* __restrict__ gamma,
                                               const float* __restrict__ beta,
                                               float* __restrict__ scale, float* __restrict__ shift,
                                               int* __restrict__ done) {
    __shared__ float reds[8][256];
    __shared__ float redq[8][256];
    const int t = threadIdx.x;
    const int cg = t & 31;        // col group: cols cg*8 .. cg*8+7
    const int rs = t >> 5;        // row slice: rows rs*32 .. rs*32+31 of this block's 256
    const long r0 = (long)blockIdx.x * 256 + (long)rs * 32;
    float s[8], q[8];
#pragma unroll
    for (int j = 0; j < 8; ++j) { s[j] = 0.f; q[j] = 0.f; }
    for (int i = 0; i < 32; ++i) {
        long r = r0 + i;
        if (r >= NNODES) break;
        uint4 u = Zu[r * 32 + cg];
        float v0 = bflo(u.x), v1 = bfhi(u.x), v2 = bflo(u.y), v3 = bfhi(u.y);
        float v4 = bflo(u.z), v5 = bfhi(u.z), v6 = bflo(u.w), v7 = bfhi(u.w);
        s[0] += v0; q[0] += v0 * v0;  s[1] += v1; q[1] += v1 * v1;
        s[2] += v2; q[2] += v2 * v2;  s[3] += v3; q[3] += v3 * v3;
        s[4] += v4; q[4] += v4 * v4;  s[5] += v5; q[5] += v5 * v5;
        s[6] += v6; q[6] += v6 * v6;  s[7] += v7; q[7] += v7 * v7;
    }
#pragma unroll
    for (int j = 0; j < 8; ++j) {
        reds[rs][cg * 8 + j] = s[j];
        redq[rs][cg * 8 + j] = q[j];
    }
    __syncthreads();
    float S = 0.f, Q = 0.f;
#pragma unroll
    for (int j = 0; j < 8; ++j) { S += reds[j][t]; Q += redq[j][t]; }
    float* rb = statr + (size_t)(blockIdx.x & (NREP - 1)) * 512;
    atomicAdd(&rb[t], S);
    atomicAdd(&rb[256 + t], Q);
    __syncthreads();                       // drains this block's atomics before done
    __shared__ int lastf;
    if (t == 0) lastf = (atomicAdd(done, 1) == (int)gridDim.x - 1) ? 1 : 0;
    __syncthreads();
    if (lastf) {
        float su = 0.f, qu = 0.f;
#pragma unroll
        for (int r = 0; r < NREP; ++r) {
            su += atomicAdd(&statr[(size_t)r * 512 + t], 0.0f);
            qu += atomicAdd(&statr[(size_t)r * 512 + 256 + t], 0.0f);
        }
        float mu = su * (1.0f / NNODES);
        float var = qu * (1.0f / NNODES) - mu * mu;
        if (var < 0.f) var = 0.f;
        float sc = gamma[t] * rsqrtf(var + EPS);
        scale[t] = sc;
        shift[t] = beta[t] - mu * sc;
    }
}

// ---------------- driver ----------------
extern "C" void kernel_launch(void* const* d_in, const int* in_sizes, int n_in,
                              void* d_out, int out_size, void* d_ws, size_t ws_size,
                              hipStream_t stream) {
    const float* x   = (const float*)d_in[0];
    const int*   ei  = (const int*)d_in[1];
    const float* W1  = (const float*)d_in[2];
    const float* g1  = (const float*)d_in[4];
    const float* be1 = (const float*)d_in[5];
    const float* W2  = (const float*)d_in[6];
    const float* g2  = (const float*)d_in[8];
    const float* be2 = (const float*)d_in[9];
    const float* W3  = (const float*)d_in[10];
    const float* b3  = (const float*)d_in[11];
    // b1 (d_in[3]) and b2 (d_in[7]) cancel exactly under BatchNorm — skipped.

    char* w = (char*)d_ws;
    size_t o = 0;
    auto alloc = [&](size_t b) { size_t r = o; o += (b + 255) & ~(size_t)255; return r; };
    int*   offs = (int*)(w + alloc((size_t)(NNODES + 1) * 4));
    float* dinv = (float*)(w + alloc((size_t)NNODES * 4));
    int*   cnt  = (int*)(w + alloc((size_t)NEB * NBUCK * 4));   // 1.6 MB
    int*   btot = (int*)(w + alloc(NBUCK * 4));
    int*   bbase= (int*)(w + alloc((NBUCK + 1) * 4));
    unsigned* ebuf = (unsigned*)(w + alloc((size_t)NEDGES * 4));
    int*   csr  = (int*)(w + alloc((size_t)NEDGES * 4));
    float* stats = (float*)(w + alloc((2 * NREP * 512 + 8) * 4)); // statr1[NREP][512], statr2[NREP][512], done1, done2
    float* bnp   = (float*)(w + alloc(4 * 256 * 4));            // scale1,shift1,scale2,shift2
    unsigned short* w1s = (unsigned short*)(w + alloc(65536));
    unsigned short* w2s = (unsigned short*)(w + alloc(131072));
    unsigned short* w3s = (unsigned short*)(w + alloc(32768));  // 4 col-groups (4th zeroed)
    __hip_bfloat16* xb   = (__hip_bfloat16*)(w + alloc((size_t)NNODES * 128 * 2));
    __hip_bfloat16* buf0 = (__hip_bfloat16*)(w + alloc((size_t)NNODES * 128 * 2)); // y0 -> T3' (stride 64)
    __hip_bfloat16* buf1 = (__hip_bfloat16*)(w + alloc((size_t)NNODES * 256 * 2)); // Z1 -> Z2
    __hip_bfloat16* buf2 = (__hip_bfloat16*)(w + alloc((size_t)NNODES * 256 * 2)); // y2'

    float* statr1 = stats;                      // NREP x 512
    float* statr2 = stats + NREP * 512;         // NREP x 512
    int*   done1 = (int*)(stats + 2 * NREP * 512);
    int*   done2 = done1 + 1;
    float* scale1 = bnp;        float* shift1 = bnp + 256;
    float* scale2 = bnp + 512;  float* shift2 = bnp + 768;

    const int SB = (NNODES + 255) / 256;  // 782
    const int GB = NNODES / 64;           // 3125 gemm blocks (200000 % 64 == 0)

    // CSR build + fused weight swizzle + replicated-stats zeroing (no memset dispatch)
    k_cnt<<<NEB + 64, 256, 0, stream>>>(ei, cnt, W1, W2, W3, w1s, w2s, w3s, (unsigned*)stats);
    k_bscan<<<(NBUCK * 64 + 255) / 256, 256, 0, stream>>>(cnt, btot);
    k_place<<<NEB, 256, 0, stream>>>(ei, ei + NEDGES, cnt, btot, bbase, ebuf);
    k_sort2<<<NBUCK, 256, 0, stream>>>(ebuf, bbase, offs, dinv, csr, x, (uint4*)xb);

    // layer 1: BN1 stats fused into GEMM epilogue (replicated), finalized by last block;
    // aggf split into 2 node-range chunks (diagnostic: keeps top-5 informative)
    for (int c = 0; c < 2; ++c)
        k_aggf<<<AGGF_CHUNK / 4, 256, 0, stream>>>((const uint4*)xb, offs, csr, dinv, (uint4*)buf0, c * AGGF_CHUNK);
    k_gemm<128, 4, 256, false, false, true><<<GB, 256, 0, stream>>>(buf0, (const __hip_bfloat16*)w1s, nullptr, nullptr, nullptr, (unsigned short*)buf1, NNODES, 256, statr1, g1, be1, scale1, shift1, done1);

    // layer 2: gemm2 applies BN1+ReLU once at LDS staging, prescales C by dinv;
    // aggb split into 4 node-range chunks (diagnostic)
    k_gemm<256, 4, 256, true, true, false><<<GB, 256, 0, stream>>>(buf1, (const __hip_bfloat16*)w2s, dinv, scale1, shift1, (unsigned short*)buf2, NNODES, 256, nullptr, nullptr, nullptr, nullptr, nullptr, nullptr);
    for (int c = 0; c < 4; ++c)
        k_aggb<<<AGGB_CHUNK / 4, 256, 0, stream>>>((const uint4*)buf2, offs, csr, dinv, (uint4*)buf1, c * AGGB_CHUNK);
    k_stats<<<SB, 256, 0, stream>>>((const uint4*)buf1, statr2, g2, be2, scale2, shift2, done2);

    // layer 3: gemm3 applies BN2+ReLU once at LDS staging, prescales C by dinv, writes 128B-padded rows;
    // then fused 4-nodes-per-wave agg+softmax reads exactly one cache line per gathered row
    k_gemm<256, 1, 64, true, true, false><<<GB, 256, 0, stream>>>(buf1, (const __hip_bfloat16*)w3s, dinv, scale2, shift2, (unsigned short*)buf0, NNODES, 40, nullptr, nullptr, nullptr, nullptr, nullptr, nullptr);
    k_agg3<<<NNODES / 16, 256, 0, stream>>>((const uint4*)buf0, offs, csr, dinv, b3, (float*)d_out);
}

// Round 13
// 874.064 us; speedup vs baseline: 1.1917x; 1.0376x over previous
//
#include <hip/hip_runtime.h>
#include <hip/hip_bf16.h>

#define NNODES 200000
#define NEDGES 3200000
#define NBUCK 782            // ceil(NNODES/256)
#define NEB 512              // edge blocks for counting sort
#define EPB (NEDGES / NEB)   // 6250 edges per block
#define CASTB 12500          // NNODES*128/8/256
#define EPS 1e-5f
#define NREP 16              // stats accumulator replicas (kills hot-address atomic queueing)

typedef __bf16 bf16x8 __attribute__((ext_vector_type(8)));
typedef float  f32x4  __attribute__((ext_vector_type(4)));
typedef float  f32x2  __attribute__((ext_vector_type(2)));

__device__ __forceinline__ float bflo(unsigned u) { return __uint_as_float(u << 16); }
__device__ __forceinline__ float bfhi(unsigned u) { return __uint_as_float(u & 0xffff0000u); }
__device__ __forceinline__ unsigned short f2b(float f) {
    return __builtin_bit_cast(unsigned short, __float2bfloat16(f));
}
__device__ __forceinline__ unsigned pk2(float a, float b) {
    return (unsigned)f2b(a) | ((unsigned)f2b(b) << 16);
}
// BN+ReLU on a packed bf16 pair, using packed f32 math (v_pk_fma_f32 / v_pk_max_f32)
__device__ __forceinline__ unsigned bnrelu_pk(unsigned u, f32x2 c, f32x2 h) {
    f32x2 v = { __uint_as_float(u << 16), __uint_as_float(u & 0xffff0000u) };
    v = __builtin_elementwise_fma(v, c, h);
    const f32x2 z = {0.f, 0.f};
    v = __builtin_elementwise_max(v, z);
    return pk2(v[0], v[1]);
}

// ---------------- weight swizzle helper ----------------
__device__ __forceinline__ void prepw_one(const float* __restrict__ W,
                                          unsigned short* __restrict__ Wswz,
                                          int K, int NOUT, int t) {
    int KSTEPS = K / 32;
    int lane = t & 63;
    int ks = (t >> 6) % KSTEPS;
    int g  = (t >> 6) / KSTEPS;
    int c = lane & 15, q = lane >> 4;
    int col = g * 16 + c;
    int k0 = ks * 32 + q * 8;
    unsigned short vals[8];
#pragma unroll
    for (int j = 0; j < 8; ++j)
        vals[j] = (col < NOUT) ? f2b(W[(size_t)(k0 + j) * NOUT + col]) : (unsigned short)0;
    *(uint4*)((char*)Wswz + (size_t)t * 16) = __builtin_bit_cast(uint4, vals);
}

// ---------------- CSR build step 1: per-block bucket histogram
// ----------------  + fused weight swizzle + stats zeroing (independent blocks) ----------------
__global__ __launch_bounds__(256) void k_cnt(const int* __restrict__ row, int* __restrict__ cnt,
                                             const float* __restrict__ W1,
                                             const float* __restrict__ W2,
                                             const float* __restrict__ W3,
                                             unsigned short* __restrict__ w1s,
                                             unsigned short* __restrict__ w2s,
                                             unsigned short* __restrict__ w3s,
                                             unsigned* __restrict__ statsz) {
    const int blk = blockIdx.x;
    if (blk >= NEB + 56) {                       // zero replicated stats + done counters
        const int zid = blk - (NEB + 56);        // 8 zero blocks
        for (int i = zid * 256 + threadIdx.x; i < 2 * NREP * 512 + 2; i += 8 * 256)
            statsz[i] = 0u;
        return;
    }
    if (blk >= NEB) {                            // weight swizzle: 56 blocks = 14336 threads
        int t = (blk - NEB) * 256 + threadIdx.x;
        if (t < 4096) prepw_one(W1, w1s, 128, 256, t);
        else if (t < 12288) prepw_one(W2, w2s, 256, 256, t - 4096);
        else if (t < 14336) prepw_one(W3, w3s, 256, 40, t - 12288);   // 4 col-groups, zero-padded
        return;
    }
    __shared__ int h[NBUCK];
    for (int i = threadIdx.x; i < NBUCK; i += 256) h[i] = 0;
    __syncthreads();
    const int e0 = blk * EPB;
    for (int i = e0 + threadIdx.x; i < e0 + EPB; i += 256)
        atomicAdd(&h[row[i] >> 8], 1);
    __syncthreads();
    for (int i = threadIdx.x; i < NBUCK; i += 256)
        cnt[(size_t)blk * NBUCK + i] = h[i];
}

__global__ __launch_bounds__(256) void k_bscan(int* __restrict__ cnt, int* __restrict__ btot) {
    const int wv = (blockIdx.x * 256 + threadIdx.x) >> 6;   // bucket
    const int lane = threadIdx.x & 63;
    if (wv >= NBUCK) return;
    int v[8]; int s = 0;
#pragma unroll
    for (int j = 0; j < 8; ++j) {
        v[j] = cnt[(size_t)(lane * 8 + j) * NBUCK + wv];
        s += v[j];
    }
    int excl = s;
#pragma unroll
    for (int o = 1; o < 64; o <<= 1) {
        int t = __shfl_up(excl, o);
        if (lane >= o) excl += t;
    }
    excl -= s;
    if (lane == 63) btot[wv] = excl + s;
    int base = excl;
#pragma unroll
    for (int j = 0; j < 8; ++j) {
        int t = v[j];
        cnt[(size_t)(lane * 8 + j) * NBUCK + wv] = base;
        base += t;
    }
}

// ---------------- place: in-block scan of btot (replaces k_btscan) + scatter ----------------
__global__ __launch_bounds__(256) void k_place(const int* __restrict__ row, const int* __restrict__ col,
                                               const int* __restrict__ cnt, const int* __restrict__ btot,
                                               int* __restrict__ bbase, unsigned* __restrict__ ebuf) {
    __shared__ int sbb[NBUCK];
    __shared__ int tp[256];
    __shared__ int base[NBUCK];
    const int t = threadIdx.x;
    // chunked exclusive scan of btot[0..NBUCK): thread t owns [t*4, t*4+4)
    int v[4]; int loc = 0;
    const int i0 = t * 4;
#pragma unroll
    for (int j = 0; j < 4; ++j) {
        int idx = i0 + j;
        v[j] = (idx < NBUCK) ? btot[idx] : 0;
        loc += v[j];
    }
    tp[t] = loc;
    __syncthreads();
    for (int off = 1; off < 256; off <<= 1) {
        int u = (t >= off) ? tp[t - off] : 0;
        __syncthreads();
        tp[t] += u;
        __syncthreads();
    }
    int run = tp[t] - loc;   // exclusive prefix of this thread's chunk
#pragma unroll
    for (int j = 0; j < 4; ++j) {
        int idx = i0 + j;
        if (idx < NBUCK) sbb[idx] = run;
        run += v[j];
    }
    __syncthreads();
    if (blockIdx.x == 0) {   // publish for k_sort2
        for (int i = t; i < NBUCK; i += 256) bbase[i] = sbb[i];
        if (t == 0) bbase[NBUCK] = NEDGES;
    }
    for (int i = t; i < NBUCK; i += 256)
        base[i] = sbb[i] + cnt[(size_t)blockIdx.x * NBUCK + i];
    __syncthreads();
    const int e0 = blockIdx.x * EPB;
    for (int i = e0 + t; i < e0 + EPB; i += 256) {
        int r = row[i], c = col[i];
        int p = atomicAdd(&base[r >> 8], 1);
        ebuf[p] = ((unsigned)(r & 255) << 18) | (unsigned)c;   // col < 2^18
    }
}

// fused: per-bucket degree count -> offs/dinv -> rank -> final CSR (graph work only)
__global__ __launch_bounds__(256) void k_sort2(const unsigned* __restrict__ ebuf,
                                               const int* __restrict__ bbase,
                                               int* __restrict__ offs, float* __restrict__ dinv,
                                               int* __restrict__ csr) {
    __shared__ int cnt[256];
    __shared__ int sofs[256];
    __shared__ int sc[256];
    const int b = blockIdx.x;
    const int t = threadIdx.x;
    const int n0 = b * 256;
    cnt[t] = 0;
    __syncthreads();
    const int s = bbase[b], e = bbase[b + 1];
    for (int i = s + t; i < e; i += 256)
        atomicAdd(&cnt[ebuf[i] >> 18], 1);
    __syncthreads();
    const int c = cnt[t];
    sc[t] = c;
    __syncthreads();
    for (int off = 1; off < 256; off <<= 1) {
        int v = (t >= off) ? sc[t - off] : 0;
        __syncthreads();
        sc[t] += v;
        __syncthreads();
    }
    const int excl = sc[t] - c;
    sofs[t] = s + excl;
    const int n = n0 + t;
    if (n < NNODES) {
        offs[n] = s + excl;
        dinv[n] = rsqrtf((float)(c + 1));
    }
    if (b == NBUCK - 1 && t == 0) offs[NNODES] = NEDGES;
    cnt[t] = 0;
    __syncthreads();
    for (int i = s + t; i < e; i += 256) {
        unsigned v = ebuf[i];
        int nl = v >> 18;
        int rank = atomicAdd(&cnt[nl], 1);
        csr[sofs[nl] + rank] = (int)(v & 0x3FFFFu);
    }
}

// ---------------- x -> prescaled bf16 cast, full occupancy (12500 blocks) ----------------
__global__ __launch_bounds__(256) void k_cast(const float* __restrict__ x,
                                              const float* __restrict__ dinv,
                                              uint4* __restrict__ xb) {
    size_t t = (size_t)blockIdx.x * 256 + threadIdx.x;
    int n = (int)(t >> 4);
    float d = dinv[n];
    const float4* xp = (const float4*)(x + t * 8);
    float4 a = xp[0], b = xp[1];
    uint4 o;
    o.x = pk2(a.x * d, a.y * d); o.y = pk2(a.z * d, a.w * d);
    o.z = pk2(b.x * d, b.y * d); o.w = pk2(b.z * d, b.w * d);
    xb[t] = o;
}

// ---------------- aggregation: F=128 rows (16 x uint4), up to 16 edges in flight ----------------
__global__ __launch_bounds__(256) void k_aggf(const uint4* __restrict__ in,
                                              const int* __restrict__ offs,
                                              const int* __restrict__ csr,
                                              const float* __restrict__ dinv,
                                              uint4* __restrict__ out) {
    const int lane = threadIdx.x & 63;
    const int grp = lane >> 4;
    const int fl = lane & 15;
    const int node = blockIdx.x * 4 + (threadIdx.x >> 6);
    const int p0 = offs[node];
    const int K = offs[node + 1] - p0 + 1;   // +1 virtual self item at k=0
    float a0=0,a1=0,a2=0,a3=0,a4=0,a5=0,a6=0,a7=0;
    auto accum = [&](uint4 u) {
        a0 += bflo(u.x); a1 += bfhi(u.x);
        a2 += bflo(u.y); a3 += bfhi(u.y);
        a4 += bflo(u.z); a5 += bfhi(u.z);
        a6 += bflo(u.w); a7 += bfhi(u.w);
    };
    int k = 0;
    for (; k + 16 <= K; k += 16) {
        int j0 = k + grp;
        int i0 = (j0 == 0) ? node : csr[p0 + j0 - 1];
        int i1 = csr[p0 + k + 3 + grp];
        int i2 = csr[p0 + k + 7 + grp];
        int i3 = csr[p0 + k + 11 + grp];
        uint4 u0 = in[(size_t)i0 * 16 + fl];
        uint4 u1 = in[(size_t)i1 * 16 + fl];
        uint4 u2 = in[(size_t)i2 * 16 + fl];
        uint4 u3 = in[(size_t)i3 * 16 + fl];
        accum(u0); accum(u1); accum(u2); accum(u3);
    }
    for (; k + 8 <= K; k += 8) {
        int j0 = k + grp;
        int i0 = (j0 == 0) ? node : csr[p0 + j0 - 1];
        int i1 = csr[p0 + k + 3 + grp];
        uint4 u0 = in[(size_t)i0 * 16 + fl];
        uint4 u1 = in[(size_t)i1 * 16 + fl];
        accum(u0); accum(u1);
    }
    for (; k + 4 <= K; k += 4) {
        int j0 = k + grp;
        int i0 = (j0 == 0) ? node : csr[p0 + j0 - 1];
        accum(in[(size_t)i0 * 16 + fl]);
    }
    int rem = K - k;
    if (grp < rem) {
        int j0 = k + grp;
        int i0 = (j0 == 0) ? node : csr[p0 + j0 - 1];
        accum(in[(size_t)i0 * 16 + fl]);
    }
#define RED(v) v += __shfl_xor(v, 32); v += __shfl_xor(v, 16);
    RED(a0) RED(a1) RED(a2) RED(a3) RED(a4) RED(a5) RED(a6) RED(a7)
#undef RED
    if (grp == 0) {
        const float d = dinv[node];
        uint4 o;
        o.x = pk2(a0 * d, a1 * d); o.y = pk2(a2 * d, a3 * d);
        o.z = pk2(a4 * d, a5 * d); o.w = pk2(a6 * d, a7 * d);
        out[(size_t)node * 16 + fl] = o;
    }
}

// ---------------- aggregation: F=256 rows (32 x uint4), 2 edges per load, unroll 4 ----------------
__global__ __launch_bounds__(256) void k_aggb(const uint4* __restrict__ in,
                                              const int* __restrict__ offs,
                                              const int* __restrict__ csr,
                                              const float* __restrict__ dinv,
                                              uint4* __restrict__ out) {
    const int lane = threadIdx.x & 63;
    const int half = lane >> 5;
    const int fl = lane & 31;
    const int node = blockIdx.x * 4 + (threadIdx.x >> 6);
    const int p0 = offs[node];
    const int K = offs[node + 1] - p0 + 1;
    float a0=0,a1=0,a2=0,a3=0,a4=0,a5=0,a6=0,a7=0;
    auto accum = [&](uint4 u) {
        a0 += bflo(u.x); a1 += bfhi(u.x);
        a2 += bflo(u.y); a3 += bfhi(u.y);
        a4 += bflo(u.z); a5 += bfhi(u.z);
        a6 += bflo(u.w); a7 += bfhi(u.w);
    };
    auto idxAt = [&](int j) -> int { return (j == 0) ? node : csr[p0 + j - 1]; };
    int k = 0;
    for (; k + 8 <= K; k += 8) {
        int i0 = idxAt(k + half);
        int i1 = csr[p0 + k + 1 + half];
        int i2 = csr[p0 + k + 3 + half];
        int i3 = csr[p0 + k + 5 + half];
        uint4 u0 = in[(size_t)i0 * 32 + fl];
        uint4 u1 = in[(size_t)i1 * 32 + fl];
        uint4 u2 = in[(size_t)i2 * 32 + fl];
        uint4 u3 = in[(size_t)i3 * 32 + fl];
        accum(u0); accum(u1); accum(u2); accum(u3);
    }
    for (; k + 2 <= K; k += 2) {
        accum(in[(size_t)idxAt(k + half) * 32 + fl]);
    }
    if (k < K && half == 0) {
        accum(in[(size_t)idxAt(k) * 32 + fl]);
    }
#define RED(v) v += __shfl_xor(v, 32);
    RED(a0) RED(a1) RED(a2) RED(a3) RED(a4) RED(a5) RED(a6) RED(a7)
#undef RED
    if (half == 0) {
        const float d = dinv[node];
        uint4 o;
        o.x = pk2(a0 * d, a1 * d); o.y = pk2(a2 * d, a3 * d);
        o.z = pk2(a4 * d, a5 * d); o.w = pk2(a6 * d, a7 * d);
        out[(size_t)node * 32 + fl] = o;
    }
}

// ---------------- final layer: 4 nodes per WAVE (16 lanes each: 3 edge-slots x 5 feat-slots),
// ---------------- amortizes the reduction+softmax tail 4x; rows padded to 128 B ----------------
__global__ __launch_bounds__(256) void k_agg3(const uint4* __restrict__ T3b,
                                              const int* __restrict__ offs,
                                              const int* __restrict__ csr,
                                              const float* __restrict__ dinv,
                                              const float* __restrict__ b3,
                                              float* __restrict__ out) {
    const int lane = threadIdx.x & 63;
    const int il   = lane & 15;          // index within 16-lane node group
    const int grp  = il / 5;             // edge slot 0..2; il==15 -> grp 3 (idle)
    const int fl   = il - grp * 5;       // feature 16B-slot 0..4
    const bool act = grp < 3;
    const int node = blockIdx.x * 16 + (threadIdx.x >> 4);
    const int p0 = offs[node];
    const int K = offs[node + 1] - p0 + 1;   // +1 virtual self item at j=0
    float a0=0,a1=0,a2=0,a3=0,a4=0,a5=0,a6=0,a7=0;
    auto accum = [&](uint4 u) {
        a0 += bflo(u.x); a1 += bfhi(u.x);
        a2 += bflo(u.y); a3 += bfhi(u.y);
        a4 += bflo(u.z); a5 += bfhi(u.z);
        a6 += bflo(u.w); a7 += bfhi(u.w);
    };
    const char* Tb = (const char*)T3b;
    if (act) {
        int k = 0;
        for (; k + 3 <= K; k += 3) {
            int j = k + grp;
            int i0 = (j == 0) ? node : csr[p0 + j - 1];
            accum(*(const uint4*)(Tb + (size_t)i0 * 128 + fl * 16));
        }
        int rem = K - k;
        if (grp < rem) {
            int j = k + grp;
            int i0 = (j == 0) ? node : csr[p0 + j - 1];
            accum(*(const uint4*)(Tb + (size_t)i0 * 128 + fl * 16));
        }
    }
    // reduce across the 3 edge-slots: lanes il<5 pull from il+5 and il+10 (same group)
#define RED3(v) { float t1 = __shfl(v, lane + 5); float t2 = __shfl(v, lane + 10); v += t1 + t2; }
    RED3(a0) RED3(a1) RED3(a2) RED3(a3) RED3(a4) RED3(a5) RED3(a6) RED3(a7)
#undef RED3
    const float d = dinv[node];
    float v[8];
    if (il < 5) {
        const float4* bp = (const float4*)(b3 + il * 8);
        float4 b01 = bp[0], b23 = bp[1];
        v[0] = a0 * d + b01.x; v[1] = a1 * d + b01.y;
        v[2] = a2 * d + b01.z; v[3] = a3 * d + b01.w;
        v[4] = a4 * d + b23.x; v[5] = a5 * d + b23.y;
        v[6] = a6 * d + b23.z; v[7] = a7 * d + b23.w;
    } else {
#pragma unroll
        for (int j = 0; j < 8; ++j) v[j] = -INFINITY;
    }
    float m = v[0];
#pragma unroll
    for (int j = 1; j < 8; ++j) m = fmaxf(m, v[j]);
    const int gbase = lane & ~15;        // first lane of this node group within the wave
    float mm = __shfl(m, gbase);
#pragma unroll
    for (int l = 1; l < 5; ++l) mm = fmaxf(mm, __shfl(m, gbase + l));
    float e = 0.f;
    if (il < 5) {
#pragma unroll
        for (int j = 0; j < 8; ++j) e += __expf(v[j] - mm);
    }
    float s = __shfl(e, gbase);
#pragma unroll
    for (int l = 1; l < 5; ++l) s += __shfl(e, gbase + l);
    float ls = __logf(s);
    if (il < 5) {
        float* op = out + (size_t)node * 40 + il * 8;
        float4 o0 = {v[0] - mm - ls, v[1] - mm - ls, v[2] - mm - ls, v[3] - mm - ls};
        float4 o1 = {v[4] - mm - ls, v[5] - mm - ls, v[6] - mm - ls, v[7] - mm - ls};
        *(float4*)op = o0;
        *(float4*)(op + 4) = o1;
    }
}

// ---------------- MFMA GEMM: whole 64-row A tile staged to LDS once, BN+ReLU at staging,
// ---------------- LDS-transposed COALESCED uint4 C-store, dinv prescale,
// ---------------- replicated fused stats + BN finalize (done-counter) ----------------
template <int K, int WNB, int CS, bool PRESCALE, bool BNA, bool STATS>
__global__ __launch_bounds__(256) void k_gemm(const __hip_bfloat16* __restrict__ A,
                                              const __hip_bfloat16* __restrict__ Wswz,
                                              const float* __restrict__ dinvp,
                                              const float* __restrict__ bnsc,
                                              const float* __restrict__ bnsh,
                                              unsigned short* __restrict__ Cout,
                                              int M, int NOUT,
                                              float* __restrict__ statr,
                                              const float* __restrict__ gamma,
                                              const float* __restrict__ beta,
                                              float* __restrict__ scale,
                                              float* __restrict__ shift,
                                              int* __restrict__ done) {
    constexpr int KSTEPS = K / 32;
    constexpr int LROW   = K + 8;            // bf16 per A-LDS row (+16B pad)
    constexpr int U4R    = K / 8;            // uint4 per A row
    constexpr int NU     = K / 32;           // uint4 staged per thread
    constexpr int RPU    = 256 / U4R;        // rows advanced per staging step
    constexpr int LROWC  = CS + 16;          // bf16 per C-LDS row: +32B pad -> row stride ≡8 dwords mod 32
    constexpr int ABYTES = 64 * LROW * 2;
    constexpr int CBYTES = 64 * LROWC * 2;
    constexpr int SBYTES = (ABYTES > CBYTES) ? ABYTES : CBYTES;
    __shared__ __align__(16) char smem[SBYTES];
    unsigned short* As = (unsigned short*)smem;
    unsigned short* Ct = (unsigned short*)smem;   // union: Ct used after compute

    const int t = threadIdx.x;
    const int lane = t & 63;
    const int wid  = t >> 6;
    const int wn = wid * (WNB * 16);
    const long rowBase = (long)blockIdx.x * 64;
    const int cl = lane & 15, q = lane >> 4;

    // ---- stage whole A tile (64 x K bf16), fully parallel loads, one barrier ----
    const int cst = t % U4R;
    const int r0l = t / U4R;
    f32x2 cp[4], hp[4];
    if constexpr (BNA) {
        const f32x2* cpp = (const f32x2*)(bnsc + cst * 8);
        const f32x2* hpp = (const f32x2*)(bnsh + cst * 8);
#pragma unroll
        for (int j = 0; j < 4; ++j) { cp[j] = cpp[j]; hp[j] = hpp[j]; }
    }
    uint4 stg[NU];
#pragma unroll
    for (int u = 0; u < NU; ++u) {
        int rl = r0l + u * RPU;
        stg[u] = *(const uint4*)((const char*)A + (size_t)(rowBase + rl) * (K * 2) + (size_t)cst * 16);
    }
#pragma unroll
    for (int u = 0; u < NU; ++u) {
        uint4 v = stg[u];
        if constexpr (BNA) {
            v.x = bnrelu_pk(v.x, cp[0], hp[0]);
            v.y = bnrelu_pk(v.y, cp[1], hp[1]);
            v.z = bnrelu_pk(v.z, cp[2], hp[2]);
            v.w = bnrelu_pk(v.w, cp[3], hp[3]);
        }
        int rl = r0l + u * RPU;
        *(uint4*)&As[rl * LROW + cst * 8] = v;
    }
    __syncthreads();

    const __hip_bfloat16* bptr[WNB];
#pragma unroll
    for (int nf = 0; nf < WNB; ++nf)
        bptr[nf] = Wswz + (size_t)(wn / 16 + nf) * KSTEPS * 512 + (size_t)lane * 8;

    f32x4 acc[4][WNB];
    const f32x4 z = {0.f, 0.f, 0.f, 0.f};
#pragma unroll
    for (int mf = 0; mf < 4; ++mf)
#pragma unroll
        for (int nf = 0; nf < WNB; ++nf) acc[mf][nf] = z;

#pragma unroll
    for (int ks = 0; ks < KSTEPS; ++ks) {
        bf16x8 a[4], b[WNB];
#pragma unroll
        for (int nf = 0; nf < WNB; ++nf)
            b[nf] = __builtin_bit_cast(bf16x8, *(const uint4*)(bptr[nf] + ks * 512));
#pragma unroll
        for (int mf = 0; mf < 4; ++mf)
            a[mf] = __builtin_bit_cast(bf16x8, *(const uint4*)&As[(mf * 16 + cl) * LROW + ks * 32 + q * 8]);
#pragma unroll
        for (int mf = 0; mf < 4; ++mf)
#pragma unroll
            for (int nf = 0; nf < WNB; ++nf)
                acc[mf][nf] = __builtin_amdgcn_mfma_f32_16x16x32_bf16(a[mf], b[nf], acc[mf][nf], 0, 0, 0);
    }

    // ---- transpose accumulators through LDS, then coalesced uint4 stores ----
    __syncthreads();   // all waves done reading As before Ct overwrites it
#pragma unroll
    for (int mf = 0; mf < 4; ++mf)
#pragma unroll
        for (int i = 0; i < 4; ++i) {
            int row = mf * 16 + q * 4 + i;
            float dv = PRESCALE ? dinvp[rowBase + row] : 1.0f;
#pragma unroll
            for (int nf = 0; nf < WNB; ++nf)
                Ct[row * LROWC + wn + nf * 16 + cl] = f2b(PRESCALE ? acc[mf][nf][i] * dv : acc[mf][nf][i]);
        }
    __syncthreads();
    constexpr int U4C = CS / 8;              // uint4 per output row
    constexpr int NC  = 64 * U4C / 256;      // per thread
#pragma unroll
    for (int u = 0; u < NC; ++u) {
        int idx = u * 256 + t;
        int row = idx / U4C, c = idx % U4C;
        uint4 v = *(const uint4*)&Ct[row * LROWC + c * 8];
        *(uint4*)&Cout[(rowBase + row) * CS + c * 8] = v;
    }

    if constexpr (STATS) {
        float* rb = statr + (size_t)(blockIdx.x & (NREP - 1)) * 512;
#pragma unroll
        for (int nf = 0; nf < WNB; ++nf) {
            float s = 0.f, s2 = 0.f;
#pragma unroll
            for (int mf = 0; mf < 4; ++mf)
#pragma unroll
                for (int i = 0; i < 4; ++i) {
                    float v = acc[mf][nf][i];
                    s += v; s2 += v * v;
                }
            s  += __shfl_xor(s, 16);  s  += __shfl_xor(s, 32);
            s2 += __shfl_xor(s2, 16); s2 += __shfl_xor(s2, 32);
            if (q == 0) {
                int col = wn + nf * 16 + cl;
                if (col < NOUT) {
                    atomicAdd(&rb[col], s);
                    atomicAdd(&rb[256 + col], s2);
                }
            }
        }
        __syncthreads();                       // drains this block's atomics before done
        __shared__ int lastf;
        if (threadIdx.x == 0) lastf = (atomicAdd(done, 1) == (int)gridDim.x - 1) ? 1 : 0;
        __syncthreads();
        if (lastf) {
            const int tt = threadIdx.x;        // 256 threads
            float su = 0.f, qu = 0.f;
#pragma unroll
            for (int r = 0; r < NREP; ++r) {
                su += atomicAdd(&statr[(size_t)r * 512 + tt], 0.0f);       // L2-coherent reads
                qu += atomicAdd(&statr[(size_t)r * 512 + 256 + tt], 0.0f);
            }
            float mu = su * (1.0f / NNODES);
            float var = qu * (1.0f / NNODES) - mu * mu;
            if (var < 0.f) var = 0.f;
            float sc = gamma[tt] * rsqrtf(var + EPS);
            scale[tt] = sc;
            shift[tt] = beta[tt] - mu * sc;
        }
    }
}

// ---------------- BN stats over bf16 matrix, vectorized, replicated accumulators ----------------
__global__ __launch_bounds__(256) void k_stats(const uint4* __restrict__ Zu,
                                               float* __restrict__ statr,
                                               const float* __restrict__ gamma,
                                               const float* __restrict__ beta,
                                               float* __restrict__ scale, float* __restrict__ shift,
                                               int* __restrict__ done) {
    __shared__ float reds[8][256];
    __shared__ float redq[8][256];
    const int t = threadIdx.x;
    const int cg = t & 31;        // col group: cols cg*8 .. cg*8+7
    const int rs = t >> 5;        // row slice: rows rs*32 .. rs*32+31 of this block's 256
    const long r0 = (long)blockIdx.x * 256 + (long)rs * 32;
    float s[8], q[8];
#pragma unroll
    for (int j = 0; j < 8; ++j) { s[j] = 0.f; q[j] = 0.f; }
    for (int i = 0; i < 32; ++i) {
        long r = r0 + i;
        if (r >= NNODES) break;
        uint4 u = Zu[r * 32 + cg];
        float v0 = bflo(u.x), v1 = bfhi(u.x), v2 = bflo(u.y), v3 = bfhi(u.y);
        float v4 = bflo(u.z), v5 = bfhi(u.z), v6 = bflo(u.w), v7 = bfhi(u.w);
        s[0] += v0; q[0] += v0 * v0;  s[1] += v1; q[1] += v1 * v1;
        s[2] += v2; q[2] += v2 * v2;  s[3] += v3; q[3] += v3 * v3;
        s[4] += v4; q[4] += v4 * v4;  s[5] += v5; q[5] += v5 * v5;
        s[6] += v6; q[6] += v6 * v6;  s[7] += v7; q[7] += v7 * v7;
    }
#pragma unroll
    for (int j = 0; j < 8; ++j) {
        reds[rs][cg * 8 + j] = s[j];
        redq[rs][cg * 8 + j] = q[j];
    }
    __syncthreads();
    float S = 0.f, Q = 0.f;
#pragma unroll
    for (int j = 0; j < 8; ++j) { S += reds[j][t]; Q += redq[j][t]; }
    float* rb = statr + (size_t)(blockIdx.x & (NREP - 1)) * 512;
    atomicAdd(&rb[t], S);
    atomicAdd(&rb[256 + t], Q);
    __syncthreads();                       // drains this block's atomics before done
    __shared__ int lastf;
    if (t == 0) lastf = (atomicAdd(done, 1) == (int)gridDim.x - 1) ? 1 : 0;
    __syncthreads();
    if (lastf) {
        float su = 0.f, qu = 0.f;
#pragma unroll
        for (int r = 0; r < NREP; ++r) {
            su += atomicAdd(&statr[(size_t)r * 512 + t], 0.0f);
            qu += atomicAdd(&statr[(size_t)r * 512 + 256 + t], 0.0f);
        }
        float mu = su * (1.0f / NNODES);
        float var = qu * (1.0f / NNODES) - mu * mu;
        if (var < 0.f) var = 0.f;
        float sc = gamma[t] * rsqrtf(var + EPS);
        scale[t] = sc;
        shift[t] = beta[t] - mu * sc;
    }
}

// ---------------- driver ----------------
extern "C" void kernel_launch(void* const* d_in, const int* in_sizes, int n_in,
                              void* d_out, int out_size, void* d_ws, size_t ws_size,
                              hipStream_t stream) {
    const float* x   = (const float*)d_in[0];
    const int*   ei  = (const int*)d_in[1];
    const float* W1  = (const float*)d_in[2];
    const float* g1  = (const float*)d_in[4];
    const float* be1 = (const float*)d_in[5];
    const float* W2  = (const float*)d_in[6];
    const float* g2  = (const float*)d_in[8];
    const float* be2 = (const float*)d_in[9];
    const float* W3  = (const float*)d_in[10];
    const float* b3  = (const float*)d_in[11];
    // b1 (d_in[3]) and b2 (d_in[7]) cancel exactly under BatchNorm — skipped.

    char* w = (char*)d_ws;
    size_t o = 0;
    auto alloc = [&](size_t b) { size_t r = o; o += (b + 255) & ~(size_t)255; return r; };
    int*   offs = (int*)(w + alloc((size_t)(NNODES + 1) * 4));
    float* dinv = (float*)(w + alloc((size_t)NNODES * 4));
    int*   cnt  = (int*)(w + alloc((size_t)NEB * NBUCK * 4));   // 1.6 MB
    int*   btot = (int*)(w + alloc(NBUCK * 4));
    int*   bbase= (int*)(w + alloc((NBUCK + 1) * 4));
    unsigned* ebuf = (unsigned*)(w + alloc((size_t)NEDGES * 4));
    int*   csr  = (int*)(w + alloc((size_t)NEDGES * 4));
    float* stats = (float*)(w + alloc((2 * NREP * 512 + 8) * 4)); // statr1[NREP][512], statr2[NREP][512], done1, done2
    float* bnp   = (float*)(w + alloc(4 * 256 * 4));            // scale1,shift1,scale2,shift2
    unsigned short* w1s = (unsigned short*)(w + alloc(65536));
    unsigned short* w2s = (unsigned short*)(w + alloc(131072));
    unsigned short* w3s = (unsigned short*)(w + alloc(32768));  // 4 col-groups (4th zeroed)
    __hip_bfloat16* xb   = (__hip_bfloat16*)(w + alloc((size_t)NNODES * 128 * 2));
    __hip_bfloat16* buf0 = (__hip_bfloat16*)(w + alloc((size_t)NNODES * 128 * 2)); // y0 -> T3' (stride 64)
    __hip_bfloat16* buf1 = (__hip_bfloat16*)(w + alloc((size_t)NNODES * 256 * 2)); // Z1 -> Z2
    __hip_bfloat16* buf2 = (__hip_bfloat16*)(w + alloc((size_t)NNODES * 256 * 2)); // y2'

    float* statr1 = stats;                      // NREP x 512
    float* statr2 = stats + NREP * 512;         // NREP x 512
    int*   done1 = (int*)(stats + 2 * NREP * 512);
    int*   done2 = done1 + 1;
    float* scale1 = bnp;        float* shift1 = bnp + 256;
    float* scale2 = bnp + 512;  float* shift2 = bnp + 768;

    const int SB = (NNODES + 255) / 256;  // 782
    const int GB = NNODES / 64;           // 3125 gemm blocks (200000 % 64 == 0)

    // CSR build + fused weight swizzle + replicated-stats zeroing (no memset dispatch)
    k_cnt<<<NEB + 64, 256, 0, stream>>>(ei, cnt, W1, W2, W3, w1s, w2s, w3s, (unsigned*)stats);
    k_bscan<<<(NBUCK * 64 + 255) / 256, 256, 0, stream>>>(cnt, btot);
    k_place<<<NEB, 256, 0, stream>>>(ei, ei + NEDGES, cnt, btot, bbase, ebuf);
    k_sort2<<<NBUCK, 256, 0, stream>>>(ebuf, bbase, offs, dinv, csr);
    k_cast<<<CASTB, 256, 0, stream>>>(x, dinv, (uint4*)xb);

    // layer 1: BN1 stats fused into GEMM epilogue (replicated), finalized by last block
    k_aggf<<<NNODES / 4, 256, 0, stream>>>((const uint4*)xb, offs, csr, dinv, (uint4*)buf0);
    k_gemm<128, 4, 256, false, false, true><<<GB, 256, 0, stream>>>(buf0, (const __hip_bfloat16*)w1s, nullptr, nullptr, nullptr, (unsigned short*)buf1, NNODES, 256, statr1, g1, be1, scale1, shift1, done1);

    // layer 2: gemm2 applies BN1+ReLU once at LDS staging, prescales C by dinv
    k_gemm<256, 4, 256, true, true, false><<<GB, 256, 0, stream>>>(buf1, (const __hip_bfloat16*)w2s, dinv, scale1, shift1, (unsigned short*)buf2, NNODES, 256, nullptr, nullptr, nullptr, nullptr, nullptr, nullptr);
    k_aggb<<<NNODES / 4, 256, 0, stream>>>((const uint4*)buf2, offs, csr, dinv, (uint4*)buf1);
    k_stats<<<SB, 256, 0, stream>>>((const uint4*)buf1, statr2, g2, be2, scale2, shift2, done2);

    // layer 3: gemm3 applies BN2+ReLU once at LDS staging, prescales C by dinv, writes 128B-padded rows;
    // then fused 4-nodes-per-wave agg+softmax reads exactly one cache line per gathered row
    k_gemm<256, 1, 64, true, true, false><<<GB, 256, 0, stream>>>(buf1, (const __hip_bfloat16*)w3s, dinv, scale2, shift2, (unsigned short*)buf0, NNODES, 40, nullptr, nullptr, nullptr, nullptr, nullptr, nullptr);
    k_agg3<<<NNODES / 16, 256, 0, stream>>>((const uint4*)buf0, offs, csr, dinv, b3, (float*)d_out);
}